// Round 2
// baseline (8131.546 us; speedup 1.0000x reference)
//
#include <hip/hip_runtime.h>
#include <hip/hip_bf16.h>

// Model constants
#define DD 1024
#define HEADS 16
#define HDIM 64
#define NLAYER 4
#define FFDIM 4096
#define NVOCAB 32000

// ---------------------------------------------------------------------------
// Embedding + decoder-level rotary: h[b,s,:] = rope(tok_emb[x[b,s]] + pos_emb[s])
// grid = B*S blocks, 512 threads (one per rotary pair)
// ---------------------------------------------------------------------------
__global__ __launch_bounds__(512) void embed_rope_kernel(
    const int* __restrict__ x, const float* __restrict__ tok_emb,
    const float* __restrict__ pos_emb, const float* __restrict__ inv_freq,
    const float* __restrict__ rbias, float* __restrict__ h, int S)
{
    const int row = blockIdx.x;      // b*S + s
    const int s = row % S;
    const int i = threadIdx.x;       // 0..511 pair index
    const int tok = x[row];
    const float* e = tok_emb + (size_t)tok * DD;
    const float* p = pos_emb + (size_t)s * DD;
    float a = e[2*i]   + p[2*i];
    float b = e[2*i+1] + p[2*i+1];
    float fr = (float)s * inv_freq[i] + rbias[(size_t)s * (DD/2) + i];
    float c = cosf(fr), sn = sinf(fr);
    h[(size_t)row*DD + 2*i]   = a*c - b*sn;
    h[(size_t)row*DD + 2*i+1] = a*sn + b*c;
}

// ---------------------------------------------------------------------------
// Per-head rotary applied in place to q or k, layout (B*S, D) = (B*S, H, HD)
// grid = B*S blocks, 512 threads: thread = head(16) x pair(32)
// ---------------------------------------------------------------------------
__global__ __launch_bounds__(512) void rope_head_kernel(
    float* __restrict__ t, const float* __restrict__ inv_freq,
    const float* __restrict__ rbias, int S)
{
    const int row = blockIdx.x;      // b*S + s
    const int s = row % S;
    const int tid = threadIdx.x;
    const int hh = tid >> 5;         // 0..15
    const int i  = tid & 31;         // 0..31
    const size_t base = (size_t)row*DD + hh*HDIM;
    float a = t[base + 2*i];
    float b = t[base + 2*i + 1];
    float fr = (float)s * inv_freq[i] + rbias[(size_t)s * (HDIM/2) + i];
    float c = cosf(fr), sn = sinf(fr);
    t[base + 2*i]     = a*c - b*sn;
    t[base + 2*i + 1] = a*sn + b*c;
}

// ---------------------------------------------------------------------------
// RMSNorm: y = x * rsqrt(mean(x^2) + 1e-8) * w  ; one block per row of 1024
// ---------------------------------------------------------------------------
__global__ __launch_bounds__(256) void rmsnorm_kernel(
    const float* __restrict__ x, const float* __restrict__ w,
    float* __restrict__ y)
{
    const int row = blockIdx.x;
    const float* xr = x + (size_t)row * DD;
    float ss = 0.f;
    for (int j = threadIdx.x; j < DD; j += 256) { float v = xr[j]; ss += v*v; }
    for (int off = 32; off > 0; off >>= 1) ss += __shfl_down(ss, off, 64);
    __shared__ float r[4];
    if ((threadIdx.x & 63) == 0) r[threadIdx.x >> 6] = ss;
    __syncthreads();
    float tot = r[0] + r[1] + r[2] + r[3];
    float sc = rsqrtf(tot * (1.0f/(float)DD) + 1e-8f);
    for (int j = threadIdx.x; j < DD; j += 256)
        y[(size_t)row*DD + j] = xr[j] * sc * w[j];
}

// ---------------------------------------------------------------------------
// Generic f32 GEMM: C = A(MxK) @ W(NxK)^T + bias + add1 + add2, optional relu
// BM=BN=64, BK=16, 256 threads, 4x4 per thread. All dims divisible.
// ---------------------------------------------------------------------------
__global__ __launch_bounds__(256) void gemm_tn_kernel(
    const float* __restrict__ A, const float* __restrict__ W,
    const float* __restrict__ bias, const float* __restrict__ add1,
    const float* __restrict__ add2, float* __restrict__ C,
    int M, int N, int K, int relu)
{
    __shared__ float As[16][68];
    __shared__ float Bs[16][68];
    const int tid = threadIdx.x;
    const int tx = tid & 15, ty = tid >> 4;
    const int m0 = blockIdx.y * 64, n0 = blockIdx.x * 64;
    const int lr = tid >> 2;          // 0..63 row within tile
    const int lk = (tid & 3) << 2;    // 0,4,8,12 k within tile
    const float* Ap = A + (size_t)(m0 + lr) * K + lk;
    const float* Wp = W + (size_t)(n0 + lr) * K + lk;
    float c[4][4] = {};
    for (int k0 = 0; k0 < K; k0 += 16) {
        float4 av = *(const float4*)(Ap + k0);
        float4 wv = *(const float4*)(Wp + k0);
        __syncthreads();
        As[lk+0][lr]=av.x; As[lk+1][lr]=av.y; As[lk+2][lr]=av.z; As[lk+3][lr]=av.w;
        Bs[lk+0][lr]=wv.x; Bs[lk+1][lr]=wv.y; Bs[lk+2][lr]=wv.z; Bs[lk+3][lr]=wv.w;
        __syncthreads();
        #pragma unroll
        for (int kk = 0; kk < 16; ++kk) {
            float a0=As[kk][ty*4+0], a1=As[kk][ty*4+1], a2=As[kk][ty*4+2], a3=As[kk][ty*4+3];
            float b0=Bs[kk][tx*4+0], b1=Bs[kk][tx*4+1], b2=Bs[kk][tx*4+2], b3=Bs[kk][tx*4+3];
            c[0][0]+=a0*b0; c[0][1]+=a0*b1; c[0][2]+=a0*b2; c[0][3]+=a0*b3;
            c[1][0]+=a1*b0; c[1][1]+=a1*b1; c[1][2]+=a1*b2; c[1][3]+=a1*b3;
            c[2][0]+=a2*b0; c[2][1]+=a2*b1; c[2][2]+=a2*b2; c[2][3]+=a2*b3;
            c[3][0]+=a3*b0; c[3][1]+=a3*b1; c[3][2]+=a3*b2; c[3][3]+=a3*b3;
        }
    }
    #pragma unroll
    for (int i = 0; i < 4; ++i) {
        const int m = m0 + ty*4 + i;
        #pragma unroll
        for (int j = 0; j < 4; ++j) {
            const int n = n0 + tx*4 + j;
            float val = c[i][j];
            if (bias) val += bias[n];
            if (add1) val += add1[(size_t)m*N + n];
            if (add2) val += add2[(size_t)m*N + n];
            if (relu) val = fmaxf(val, 0.f);
            C[(size_t)m*N + n] = val;
        }
    }
}

// ---------------------------------------------------------------------------
// Attention for one (b, head, query) row.
// NOTE: reference multiplies scores by the causal mask (0, NOT -inf), so
// future positions carry score 0 INTO the softmax and get nonzero weight.
// scaled_zero multiplies unmasked scores where k[...,0]==0 exactly.
// grid = (S, B*HEADS), 256 threads.
// ---------------------------------------------------------------------------
__global__ __launch_bounds__(256) void attn_kernel(
    const float* __restrict__ q, const float* __restrict__ kmat,
    const float* __restrict__ v, const float* __restrict__ fptr,
    float* __restrict__ o, int S)
{
    __shared__ float qv[HDIM];
    __shared__ float sc[1024];
    __shared__ float red[256];
    __shared__ float pv[4][HDIM];
    const int qi = blockIdx.x;
    const int bh = blockIdx.y;        // b*HEADS + h
    const int b = bh >> 4, hh = bh & 15;
    const int t = threadIdx.x;

    float f = fptr[0];
    float sp = (f > 20.f) ? f : log1pf(expf(f));
    float zf = fminf(fmaxf(sp, 1e-5f), 0.1f);

    const size_t rowbase = ((size_t)(b*S + qi))*DD + hh*HDIM;
    if (t < HDIM) qv[t] = q[rowbase + t];
    __syncthreads();

    float local[4];
    float lmax = -3.0e38f;
    #pragma unroll
    for (int j = 0; j < 4; ++j) {
        const int ki = t*4 + j;
        float sval = 0.f;
        if (ki <= qi) {
            const float* kr = kmat + ((size_t)(b*S + ki))*DD + hh*HDIM;
            float dot = 0.f;
            #pragma unroll
            for (int d = 0; d < HDIM; ++d) dot += qv[d] * kr[d];
            sval = dot * 0.125f;              // HD^-0.5 = 1/8
            if (kr[0] == 0.0f) sval *= zf;    // scaled_zero on post-rotary k[...,0]
        }
        local[j] = sval;
        lmax = fmaxf(lmax, sval);
    }
    red[t] = lmax;
    __syncthreads();
    for (int ofs = 128; ofs > 0; ofs >>= 1) {
        if (t < ofs) red[t] = fmaxf(red[t], red[t+ofs]);
        __syncthreads();
    }
    const float mx = red[0];
    __syncthreads();
    float lsum = 0.f;
    #pragma unroll
    for (int j = 0; j < 4; ++j) {
        float p = expf(local[j] - mx);
        sc[t*4 + j] = p;
        lsum += p;
    }
    red[t] = lsum;
    __syncthreads();
    for (int ofs = 128; ofs > 0; ofs >>= 1) {
        if (t < ofs) red[t] += red[t+ofs];
        __syncthreads();
    }
    const float inv = 1.0f / red[0];

    // PV: thread (d,g): d = lane dim, g = key-quarter; coalesced v reads
    const int d = t & 63, g = t >> 6;
    const float* vb = v + (size_t)(b*S)*DD + hh*HDIM + d;
    float acc = 0.f;
    const int k0 = g * 256;
    for (int ki = k0; ki < k0 + 256; ++ki)
        acc += sc[ki] * vb[(size_t)ki * DD];
    pv[g][d] = acc;
    __syncthreads();
    if (t < HDIM)
        o[rowbase + t] = (pv[0][t] + pv[1][t] + pv[2][t] + pv[3][t]) * inv;
}

// ---------------------------------------------------------------------------
extern "C" void kernel_launch(void* const* d_in, const int* in_sizes, int n_in,
                              void* d_out, int out_size, void* d_ws, size_t ws_size,
                              hipStream_t stream)
{
    const int S = 1024;
    const int B = in_sizes[0] / S;     // 2
    const int M = B * S;               // 2048

    const int*   x       = (const int*)  d_in[0];
    const float* tok_emb = (const float*)d_in[2];
    const float* pos_emb = (const float*)d_in[3];
    const float* rif     = (const float*)d_in[4];
    const float* rbias   = (const float*)d_in[5];
    const float* brif    = (const float*)d_in[6];
    const float* bbias   = (const float*)d_in[7];
    const float* lna     = (const float*)d_in[8];
    const float* qw      = (const float*)d_in[9];
    const float* qb      = (const float*)d_in[10];
    const float* kw      = (const float*)d_in[11];
    const float* vw      = (const float*)d_in[12];
    const float* vb      = (const float*)d_in[13];
    const float* ow      = (const float*)d_in[14];
    const float* ob      = (const float*)d_in[15];
    const float* factor  = (const float*)d_in[16];
    const float* lnc     = (const float*)d_in[17];
    const float* w1      = (const float*)d_in[18];
    const float* b1      = (const float*)d_in[19];
    const float* w2      = (const float*)d_in[20];
    const float* b2      = (const float*)d_in[21];
    const float* lnd     = (const float*)d_in[22];

    float* out = (float*)d_out;
    const size_t U = (size_t)M * DD;   // one activation buffer (2M floats)
    // Scratch lives in the front of d_out (overwritten by final logits GEMM,
    // which reads only hn from d_ws). 10U = 20.97M floats << 65.5M out floats.
    float* q     = out + 0*U;
    float* k     = out + 1*U;
    float* v     = out + 2*U;
    float* attno = out + 3*U;
    float* h2    = out + 4*U;
    float* h     = out + 5*U;
    float* m1    = out + 6*U;          // M x FFDIM = 4U
    float* hn    = (float*)d_ws;       // 8 MB

    dim3 gD(DD/64,    M/64);
    dim3 gF(FFDIM/64, M/64);
    dim3 gV(NVOCAB/64, M/64);

    embed_rope_kernel<<<M, 512, 0, stream>>>(x, tok_emb, pos_emb, rif, rbias, h, S);

    for (int l = 0; l < NLAYER; ++l) {
        const size_t wo = (size_t)l * DD * DD;
        const size_t fo = (size_t)l * FFDIM * DD;
        rmsnorm_kernel<<<M, 256, 0, stream>>>(h, lna + l*DD, hn);
        gemm_tn_kernel<<<gD, 256, 0, stream>>>(hn, qw + wo, qb + l*DD, nullptr, nullptr, q, M, DD, DD, 0);
        gemm_tn_kernel<<<gD, 256, 0, stream>>>(hn, kw + wo, nullptr,   nullptr, nullptr, k, M, DD, DD, 0);
        gemm_tn_kernel<<<gD, 256, 0, stream>>>(hn, vw + wo, vb + l*DD, nullptr, nullptr, v, M, DD, DD, 0);
        rope_head_kernel<<<M, 512, 0, stream>>>(q, brif, bbias, S);
        rope_head_kernel<<<M, 512, 0, stream>>>(k, brif, bbias, S);
        attn_kernel<<<dim3(S, B*HEADS), 256, 0, stream>>>(q, k, v, factor + l, attno, S);
        // h2 = attno @ ow^T + ob + h
        gemm_tn_kernel<<<gD, 256, 0, stream>>>(attno, ow + wo, ob + l*DD, h, nullptr, h2, M, DD, DD, 0);
        rmsnorm_kernel<<<M, 256, 0, stream>>>(h2, lnc + l*DD, hn);
        gemm_tn_kernel<<<gF, 256, 0, stream>>>(hn, w1 + fo, b1 + l*FFDIM, nullptr, nullptr, m1, M, FFDIM, DD, 1);
        // h_new = m1 @ w2^T + b2 + h2 + h   (== 2*h_old + attn + mlp)
        gemm_tn_kernel<<<gD, 256, 0, stream>>>(m1, w2 + fo, b2 + l*DD, h2, h, h, M, DD, FFDIM, 0);
    }

    rmsnorm_kernel<<<M, 256, 0, stream>>>(h, lnd, hn);
    gemm_tn_kernel<<<gV, 256, 0, stream>>>(hn, tok_emb, nullptr, nullptr, nullptr, out, M, NVOCAB, DD, 0);
}

// Round 3
// 3318.213 us; speedup vs baseline: 2.4506x; 2.4506x over previous
//
#include <hip/hip_runtime.h>
#include <hip/hip_bf16.h>

#define DD 1024
#define HEADS 16
#define HDIM 64
#define NLAYER 4
#define FFDIM 4096
#define NVOCAB 32000
#define SEQ 1024

typedef __bf16 bf16_t;
typedef __bf16 bf16x8 __attribute__((ext_vector_type(8)));
typedef __bf16 bf16x4v __attribute__((ext_vector_type(4)));
typedef float f32x4 __attribute__((ext_vector_type(4)));

#define MFMA16(a, b, c) __builtin_amdgcn_mfma_f32_16x16x32_bf16((a), (b), (c), 0, 0, 0)

static __device__ __forceinline__ bf16x8 pack8(float4 u, float4 v) {
    bf16x8 r;
    r[0] = (bf16_t)u.x; r[1] = (bf16_t)u.y; r[2] = (bf16_t)u.z; r[3] = (bf16_t)u.w;
    r[4] = (bf16_t)v.x; r[5] = (bf16_t)v.y; r[6] = (bf16_t)v.z; r[7] = (bf16_t)v.w;
    return r;
}

// ---------------------------------------------------------------------------
// Embedding + decoder-level rotary
// ---------------------------------------------------------------------------
__global__ __launch_bounds__(512) void embed_rope_kernel(
    const int* __restrict__ x, const float* __restrict__ tok_emb,
    const float* __restrict__ pos_emb, const float* __restrict__ inv_freq,
    const float* __restrict__ rbias, float* __restrict__ h, int S)
{
    const int row = blockIdx.x;      // b*S + s
    const int s = row % S;
    const int i = threadIdx.x;       // 0..511 pair index
    const int tok = x[row];
    const float* e = tok_emb + (size_t)tok * DD;
    const float* p = pos_emb + (size_t)s * DD;
    float a = e[2*i]   + p[2*i];
    float b = e[2*i+1] + p[2*i+1];
    float fr = (float)s * inv_freq[i] + rbias[(size_t)s * (DD/2) + i];
    float c = cosf(fr), sn = sinf(fr);
    h[(size_t)row*DD + 2*i]   = a*c - b*sn;
    h[(size_t)row*DD + 2*i+1] = a*sn + b*c;
}

// ---------------------------------------------------------------------------
// Per-head rotary in place; for K also emits zmult[bh][s] (scaled_zero table)
// ---------------------------------------------------------------------------
__global__ __launch_bounds__(512) void rope_head_kernel(
    float* __restrict__ t, const float* __restrict__ inv_freq,
    const float* __restrict__ rbias, const float* __restrict__ fptr,
    float* __restrict__ zmult, int S)
{
    const int row = blockIdx.x;      // b*S + s
    const int s = row % S;
    const int tid = threadIdx.x;
    const int hh = tid >> 5;         // 0..15
    const int i  = tid & 31;         // 0..31
    const size_t base = (size_t)row*DD + hh*HDIM;
    float a = t[base + 2*i];
    float b = t[base + 2*i + 1];
    float fr = (float)s * inv_freq[i] + rbias[(size_t)s * (HDIM/2) + i];
    float c = cosf(fr), sn = sinf(fr);
    float na = a*c - b*sn;
    float nb = a*sn + b*c;
    t[base + 2*i]     = na;
    t[base + 2*i + 1] = nb;
    if (zmult != nullptr && i == 0) {
        float f = fptr[0];
        float sp = (f > 20.f) ? f : log1pf(expf(f));
        float zf = fminf(fmaxf(sp, 1e-5f), 0.1f);
        int bb = row / S;
        zmult[(size_t)(bb*HEADS + hh)*S + s] = (na == 0.0f) ? zf : 1.0f;
    }
}

// ---------------------------------------------------------------------------
// RMSNorm
// ---------------------------------------------------------------------------
__global__ __launch_bounds__(256) void rmsnorm_kernel(
    const float* __restrict__ x, const float* __restrict__ w,
    float* __restrict__ y)
{
    const int row = blockIdx.x;
    const float* xr = x + (size_t)row * DD;
    float ss = 0.f;
    for (int j = threadIdx.x; j < DD; j += 256) { float v = xr[j]; ss += v*v; }
    for (int off = 32; off > 0; off >>= 1) ss += __shfl_down(ss, off, 64);
    __shared__ float r[4];
    if ((threadIdx.x & 63) == 0) r[threadIdx.x >> 6] = ss;
    __syncthreads();
    float tot = r[0] + r[1] + r[2] + r[3];
    float sc = rsqrtf(tot * (1.0f/(float)DD) + 1e-8f);
    for (int j = threadIdx.x; j < DD; j += 256)
        y[(size_t)row*DD + j] = xr[j] * sc * w[j];
}

// ---------------------------------------------------------------------------
// Generic bf16-MFMA GEMM, f32 in / f32 out (mode 0) or transposed bf16 out
// (mode 1: Cvt[b][h][d][s], for V). C = A(MxK) @ W(NxK)^T + bias + add1 + add2.
// 128x128 tile, BK=64, 256 threads (4 waves, each 64x64 = 4x4 frags of 16x16).
// A-frag: lane holds A[row=l&15][k=(l>>4)*8 + e]; B-frag same over N; C/D:
// col=l&15, row=(l>>4)*4+r (m89/m91-verified layouts).
// ---------------------------------------------------------------------------
__global__ __launch_bounds__(256) void gemm_mfma(
    const float* __restrict__ A, const float* __restrict__ W,
    const float* __restrict__ bias, const float* __restrict__ add1,
    const float* __restrict__ add2, float* __restrict__ C,
    bf16_t* __restrict__ Cvt,
    int M, int N, int K, int relu, int mode)
{
    __shared__ __align__(16) bf16_t As[128][72];
    __shared__ __align__(16) bf16_t Bs[128][72];
    const int tid = threadIdx.x;
    const int m0 = blockIdx.y * 128, n0 = blockIdx.x * 128;
    const int r  = tid >> 1;            // 0..127 staging row
    const int kq = (tid & 1) * 32;      // staging k-offset
    const int l  = tid & 63, w = tid >> 6;
    const int wr = (w >> 1) * 64, wc = (w & 1) * 64;
    const int lr = l & 15, lk = (l >> 4) * 8;

    const float* Ap = A + (size_t)(m0 + r) * K + kq;
    const float* Wp = W + (size_t)(n0 + r) * K + kq;

    f32x4 z4 = {0.f, 0.f, 0.f, 0.f};
    f32x4 acc[4][4];
    #pragma unroll
    for (int i = 0; i < 4; ++i)
        #pragma unroll
        for (int j = 0; j < 4; ++j) acc[i][j] = z4;

    for (int k0 = 0; k0 < K; k0 += 64) {
        float4 av[8], wv[8];
        #pragma unroll
        for (int j = 0; j < 8; ++j) {
            av[j] = *(const float4*)(Ap + k0 + 4*j);
            wv[j] = *(const float4*)(Wp + k0 + 4*j);
        }
        __syncthreads();
        #pragma unroll
        for (int j = 0; j < 4; ++j) {
            *(bf16x8*)&As[r][kq + 8*j] = pack8(av[2*j], av[2*j+1]);
            *(bf16x8*)&Bs[r][kq + 8*j] = pack8(wv[2*j], wv[2*j+1]);
        }
        __syncthreads();
        #pragma unroll
        for (int kk = 0; kk < 2; ++kk) {
            bf16x8 afr[4], bfr[4];
            #pragma unroll
            for (int i = 0; i < 4; ++i)
                afr[i] = *(const bf16x8*)&As[wr + i*16 + lr][kk*32 + lk];
            #pragma unroll
            for (int j = 0; j < 4; ++j)
                bfr[j] = *(const bf16x8*)&Bs[wc + j*16 + lr][kk*32 + lk];
            #pragma unroll
            for (int i = 0; i < 4; ++i)
                #pragma unroll
                for (int j = 0; j < 4; ++j)
                    acc[i][j] = MFMA16(afr[i], bfr[j], acc[i][j]);
        }
    }

    #pragma unroll
    for (int i = 0; i < 4; ++i) {
        #pragma unroll
        for (int j = 0; j < 4; ++j) {
            const int col  = n0 + wc + j*16 + lr;
            const int row0 = m0 + wr + i*16 + (l >> 4)*4;
            const float bv = bias ? bias[col] : 0.f;
            #pragma unroll
            for (int r2 = 0; r2 < 4; ++r2) {
                const int row = row0 + r2;
                float val = acc[i][j][r2] + bv;
                if (add1) val += add1[(size_t)row*N + col];
                if (add2) val += add2[(size_t)row*N + col];
                if (relu) val = fmaxf(val, 0.f);
                if (mode == 0) {
                    C[(size_t)row*N + col] = val;
                } else {
                    // V transposed store: row=(b,s), col=(h,d) -> Vt[b][h][d][s]
                    const int bb = row >> 10, s = row & (SEQ - 1);
                    const int hh = col >> 6,  d = col & 63;
                    Cvt[((size_t)(bb*HEADS + hh)*HDIM + d)*SEQ + s] = (bf16_t)val;
                }
            }
        }
    }
}

// ---------------------------------------------------------------------------
// QK^T per (b,h): S_bf[bh][q][key] = (key<=q) ? dot*0.125*zmult[bh][key] : 0
// K(contraction)=64 -> single staged step. grid (8 keytiles, 8 qtiles, 32 bh).
// Masked entries are EXACT 0 and participate in softmax (reference multiplies
// scores by the causal mask, it does not use -inf).
// ---------------------------------------------------------------------------
__global__ __launch_bounds__(256) void qk_kernel(
    const float* __restrict__ q, const float* __restrict__ k,
    const float* __restrict__ zmult, bf16_t* __restrict__ Sout, int S)
{
    __shared__ __align__(16) bf16_t As[128][72];
    __shared__ __align__(16) bf16_t Bs[128][72];
    const int tid = threadIdx.x;
    const int bh = blockIdx.z;
    const int b = bh >> 4, hh = bh & 15;
    const int q0 = blockIdx.y * 128, c0 = blockIdx.x * 128;
    const int l = tid & 63, w = tid >> 6;
    const int wr = (w >> 1) * 64, wc = (w & 1) * 64;
    const int lr = l & 15, lk = (l >> 4) * 8;

    if (c0 > q0 + 127) {   // fully masked tile: write exact zeros
        #pragma unroll
        for (int i = 0; i < 4; ++i)
            #pragma unroll
            for (int j = 0; j < 4; ++j) {
                const int key  = c0 + wc + j*16 + lr;
                const int row0 = q0 + wr + i*16 + (l >> 4)*4;
                #pragma unroll
                for (int r2 = 0; r2 < 4; ++r2)
                    Sout[((size_t)bh*S + row0 + r2)*S + key] = (bf16_t)0.f;
            }
        return;
    }

    const int r = tid >> 1, half = (tid & 1) * 32;
    {
        const float* qp = q + ((size_t)(b*S + q0 + r))*DD + hh*HDIM + half;
        const float* kp = k + ((size_t)(b*S + c0 + r))*DD + hh*HDIM + half;
        float4 av[8], wv[8];
        #pragma unroll
        for (int j = 0; j < 8; ++j) {
            av[j] = *(const float4*)(qp + 4*j);
            wv[j] = *(const float4*)(kp + 4*j);
        }
        #pragma unroll
        for (int j = 0; j < 4; ++j) {
            *(bf16x8*)&As[r][half + 8*j] = pack8(av[2*j], av[2*j+1]);
            *(bf16x8*)&Bs[r][half + 8*j] = pack8(wv[2*j], wv[2*j+1]);
        }
        __syncthreads();
    }

    f32x4 z4 = {0.f, 0.f, 0.f, 0.f};
    f32x4 acc[4][4];
    #pragma unroll
    for (int i = 0; i < 4; ++i)
        #pragma unroll
        for (int j = 0; j < 4; ++j) acc[i][j] = z4;

    #pragma unroll
    for (int kk = 0; kk < 2; ++kk) {
        bf16x8 afr[4], bfr[4];
        #pragma unroll
        for (int i = 0; i < 4; ++i)
            afr[i] = *(const bf16x8*)&As[wr + i*16 + lr][kk*32 + lk];
        #pragma unroll
        for (int j = 0; j < 4; ++j)
            bfr[j] = *(const bf16x8*)&Bs[wc + j*16 + lr][kk*32 + lk];
        #pragma unroll
        for (int i = 0; i < 4; ++i)
            #pragma unroll
            for (int j = 0; j < 4; ++j)
                acc[i][j] = MFMA16(afr[i], bfr[j], acc[i][j]);
    }

    #pragma unroll
    for (int i = 0; i < 4; ++i) {
        #pragma unroll
        for (int j = 0; j < 4; ++j) {
            const int key  = c0 + wc + j*16 + lr;
            const int row0 = q0 + wr + i*16 + (l >> 4)*4;
            const float zm = zmult[(size_t)bh*S + key];
            #pragma unroll
            for (int r2 = 0; r2 < 4; ++r2) {
                const int qi = row0 + r2;
                float val = acc[i][j][r2] * 0.125f;   // HD^-0.5
                val = (key <= qi) ? val * zm : 0.f;
                Sout[((size_t)bh*S + qi)*S + key] = (bf16_t)val;
            }
        }
    }
}

// ---------------------------------------------------------------------------
// Row softmax, in place over bf16 rows of length 1024. f32 internally.
// ---------------------------------------------------------------------------
__global__ __launch_bounds__(256) void softmax_rows(bf16_t* __restrict__ Sbuf)
{
    const size_t row = blockIdx.x;
    bf16_t* p = Sbuf + row * SEQ;
    const int t = threadIdx.x;
    bf16x4v x = *(const bf16x4v*)(p + t*4);
    float v0 = (float)x[0], v1 = (float)x[1], v2 = (float)x[2], v3 = (float)x[3];

    float m = fmaxf(fmaxf(v0, v1), fmaxf(v2, v3));
    for (int off = 32; off > 0; off >>= 1) m = fmaxf(m, __shfl_xor(m, off, 64));
    __shared__ float rm[4], rs[4];
    if ((t & 63) == 0) rm[t >> 6] = m;
    __syncthreads();
    m = fmaxf(fmaxf(rm[0], rm[1]), fmaxf(rm[2], rm[3]));

    float e0 = expf(v0 - m), e1 = expf(v1 - m), e2 = expf(v2 - m), e3 = expf(v3 - m);
    float s = e0 + e1 + e2 + e3;
    for (int off = 32; off > 0; off >>= 1) s += __shfl_xor(s, off, 64);
    if ((t & 63) == 0) rs[t >> 6] = s;
    __syncthreads();
    const float inv = 1.0f / (rs[0] + rs[1] + rs[2] + rs[3]);

    bf16x4v o;
    o[0] = (bf16_t)(e0 * inv); o[1] = (bf16_t)(e1 * inv);
    o[2] = (bf16_t)(e2 * inv); o[3] = (bf16_t)(e3 * inv);
    *(bf16x4v*)(p + t*4) = o;
}

// ---------------------------------------------------------------------------
// PV per (b,h): O[q][d] = sum_k P[q][k] * Vt[d][k].  M=S, N=64, K=S.
// Tile 128x64, BK=64, 4 waves each 32x64 (2x4 frags). bf16 inputs direct.
// grid (1, S/128, B*HEADS). Output written into attno f32 [row][DD] layout.
// ---------------------------------------------------------------------------
__global__ __launch_bounds__(256) void pv_kernel(
    const bf16_t* __restrict__ P, const bf16_t* __restrict__ Vt,
    float* __restrict__ O, int S)
{
    __shared__ __align__(16) bf16_t As[128][72];
    __shared__ __align__(16) bf16_t Bs[64][72];
    const int tid = threadIdx.x;
    const int bh = blockIdx.z, b = bh >> 4, hh = bh & 15;
    const int q0 = blockIdx.y * 128;
    const int l = tid & 63, w = tid >> 6;
    const int wr = w * 32;
    const int lr = l & 15, lk = (l >> 4) * 8;

    const bf16_t* Pp = P  + ((size_t)bh * S + q0) * S;
    const bf16_t* Vp = Vt + ((size_t)bh * HDIM) * S;

    const int ra = tid >> 1, ha = (tid & 1) * 32;  // A staging: 128 rows x 32
    const int rb = tid >> 2, hb = (tid & 3) * 16;  // B staging: 64 rows x 16

    f32x4 z4 = {0.f, 0.f, 0.f, 0.f};
    f32x4 acc[2][4];
    #pragma unroll
    for (int i = 0; i < 2; ++i)
        #pragma unroll
        for (int j = 0; j < 4; ++j) acc[i][j] = z4;

    for (int k0 = 0; k0 < S; k0 += 64) {
        bf16x8 a0 = *(const bf16x8*)(Pp + (size_t)ra*S + k0 + ha + 0);
        bf16x8 a1 = *(const bf16x8*)(Pp + (size_t)ra*S + k0 + ha + 8);
        bf16x8 a2 = *(const bf16x8*)(Pp + (size_t)ra*S + k0 + ha + 16);
        bf16x8 a3 = *(const bf16x8*)(Pp + (size_t)ra*S + k0 + ha + 24);
        bf16x8 b0 = *(const bf16x8*)(Vp + (size_t)rb*S + k0 + hb + 0);
        bf16x8 b1 = *(const bf16x8*)(Vp + (size_t)rb*S + k0 + hb + 8);
        __syncthreads();
        *(bf16x8*)&As[ra][ha + 0]  = a0;
        *(bf16x8*)&As[ra][ha + 8]  = a1;
        *(bf16x8*)&As[ra][ha + 16] = a2;
        *(bf16x8*)&As[ra][ha + 24] = a3;
        *(bf16x8*)&Bs[rb][hb + 0]  = b0;
        *(bf16x8*)&Bs[rb][hb + 8]  = b1;
        __syncthreads();
        #pragma unroll
        for (int kk = 0; kk < 2; ++kk) {
            bf16x8 afr[2], bfr[4];
            #pragma unroll
            for (int i = 0; i < 2; ++i)
                afr[i] = *(const bf16x8*)&As[wr + i*16 + lr][kk*32 + lk];
            #pragma unroll
            for (int j = 0; j < 4; ++j)
                bfr[j] = *(const bf16x8*)&Bs[j*16 + lr][kk*32 + lk];
            #pragma unroll
            for (int i = 0; i < 2; ++i)
                #pragma unroll
                for (int j = 0; j < 4; ++j)
                    acc[i][j] = MFMA16(afr[i], bfr[j], acc[i][j]);
        }
    }

    #pragma unroll
    for (int i = 0; i < 2; ++i) {
        #pragma unroll
        for (int j = 0; j < 4; ++j) {
            const int d    = j*16 + lr;
            const int row0 = q0 + wr + i*16 + (l >> 4)*4;
            #pragma unroll
            for (int r2 = 0; r2 < 4; ++r2)
                O[((size_t)(b*S + row0 + r2))*DD + hh*HDIM + d] = acc[i][j][r2];
        }
    }
}

// ---------------------------------------------------------------------------
extern "C" void kernel_launch(void* const* d_in, const int* in_sizes, int n_in,
                              void* d_out, int out_size, void* d_ws, size_t ws_size,
                              hipStream_t stream)
{
    const int S = SEQ;
    const int B = in_sizes[0] / S;     // 2
    const int M = B * S;               // 2048
    const int BH = B * HEADS;          // 32

    const int*   x       = (const int*)  d_in[0];
    const float* tok_emb = (const float*)d_in[2];
    const float* pos_emb = (const float*)d_in[3];
    const float* rif     = (const float*)d_in[4];
    const float* rbias   = (const float*)d_in[5];
    const float* brif    = (const float*)d_in[6];
    const float* bbias   = (const float*)d_in[7];
    const float* lna     = (const float*)d_in[8];
    const float* qw      = (const float*)d_in[9];
    const float* qb      = (const float*)d_in[10];
    const float* kw      = (const float*)d_in[11];
    const float* vw      = (const float*)d_in[12];
    const float* vbias   = (const float*)d_in[13];
    const float* ow      = (const float*)d_in[14];
    const float* ob      = (const float*)d_in[15];
    const float* factor  = (const float*)d_in[16];
    const float* lnc     = (const float*)d_in[17];
    const float* w1      = (const float*)d_in[18];
    const float* b1      = (const float*)d_in[19];
    const float* w2      = (const float*)d_in[20];
    const float* b2      = (const float*)d_in[21];
    const float* lnd     = (const float*)d_in[22];

    float* out = (float*)d_out;
    const size_t U = (size_t)M * DD;   // 2M floats = 8 MiB
    // out layout (all scratch overwritten by final logits GEMM):
    float*  q     = out + 0*U;
    float*  k     = out + 1*U;
    bf16_t* vt    = (bf16_t*)(out + 2*U);     // Vt[b][h][d][S] bf16, 4 MiB
    float*  attno = out + 3*U;
    float*  h2    = out + 4*U;
    float*  h     = out + 5*U;
    float*  m1    = out + 6*U;                // M x FFDIM (4U)
    bf16_t* Sbuf  = (bf16_t*)(out + 10*U);    // S[bh][q][key] bf16, 64 MiB
    float*  zmult = out + 18*U;               // [bh][key], 128 KiB
    float*  hn    = (float*)d_ws;             // 8 MiB

    dim3 gD(DD/128,     M/128);
    dim3 gF(FFDIM/128,  M/128);
    dim3 gV(NVOCAB/128, M/128);
    dim3 gQK(S/128, S/128, BH);
    dim3 gPV(1, S/128, BH);

    embed_rope_kernel<<<M, 512, 0, stream>>>(x, tok_emb, pos_emb, rif, rbias, h, S);

    for (int l = 0; l < NLAYER; ++l) {
        const size_t wo = (size_t)l * DD * DD;
        const size_t fo = (size_t)l * FFDIM * DD;
        rmsnorm_kernel<<<M, 256, 0, stream>>>(h, lna + l*DD, hn);
        gemm_mfma<<<gD, 256, 0, stream>>>(hn, qw + wo, qb + l*DD, nullptr, nullptr, q, nullptr, M, DD, DD, 0, 0);
        gemm_mfma<<<gD, 256, 0, stream>>>(hn, kw + wo, nullptr,   nullptr, nullptr, k, nullptr, M, DD, DD, 0, 0);
        gemm_mfma<<<gD, 256, 0, stream>>>(hn, vw + wo, vbias + l*DD, nullptr, nullptr, nullptr, vt, M, DD, DD, 0, 1);
        rope_head_kernel<<<M, 512, 0, stream>>>(q, brif, bbias, nullptr, nullptr, S);
        rope_head_kernel<<<M, 512, 0, stream>>>(k, brif, bbias, factor + l, zmult, S);
        qk_kernel<<<gQK, 256, 0, stream>>>(q, k, zmult, Sbuf, S);
        softmax_rows<<<BH * S, 256, 0, stream>>>(Sbuf);
        pv_kernel<<<gPV, 256, 0, stream>>>(Sbuf, vt, attno, S);
        // h2 = attno @ ow^T + ob + h
        gemm_mfma<<<gD, 256, 0, stream>>>(attno, ow + wo, ob + l*DD, h, nullptr, h2, nullptr, M, DD, DD, 0, 0);
        rmsnorm_kernel<<<M, 256, 0, stream>>>(h2, lnc + l*DD, hn);
        gemm_mfma<<<gF, 256, 0, stream>>>(hn, w1 + fo, b1 + l*FFDIM, nullptr, nullptr, m1, nullptr, M, FFDIM, DD, 1, 0);
        // h_new = m1 @ w2^T + b2 + h2 + h   (== 2*h_old + attn + mlp)
        gemm_mfma<<<gD, 256, 0, stream>>>(m1, w2 + fo, b2 + l*DD, h2, h, h, nullptr, M, DD, FFDIM, 0, 0);
    }

    rmsnorm_kernel<<<M, 256, 0, stream>>>(h, lnd, hn);
    gemm_mfma<<<gV, 256, 0, stream>>>(hn, tok_emb, nullptr, nullptr, nullptr, out, nullptr, M, NVOCAB, DD, 0, 0);
}

// Round 4
// 2096.893 us; speedup vs baseline: 3.8779x; 1.5824x over previous
//
#include <hip/hip_runtime.h>
#include <hip/hip_bf16.h>

#define DD 1024
#define HEADS 16
#define HDIM 64
#define NLAYER 4
#define FFDIM 4096
#define NVOCAB 32000
#define SEQ 1024

typedef __bf16 bf16_t;
typedef __bf16 bf16x8 __attribute__((ext_vector_type(8)));
typedef __bf16 bf16x4v __attribute__((ext_vector_type(4)));
typedef float f32x4 __attribute__((ext_vector_type(4)));

#define MFMA16(a, b, c) __builtin_amdgcn_mfma_f32_16x16x32_bf16((a), (b), (c), 0, 0, 0)

// async global->LDS, 16B per lane, dest = wave-uniform base + lane*16
#define GLD16(gp, lp) \
    __builtin_amdgcn_global_load_lds( \
        (const __attribute__((address_space(1))) void*)(gp), \
        (__attribute__((address_space(3))) void*)(lp), 16, 0, 0)

static __device__ __forceinline__ bf16x8 pack8(float4 u, float4 v) {
    bf16x8 r;
    r[0] = (bf16_t)u.x; r[1] = (bf16_t)u.y; r[2] = (bf16_t)u.z; r[3] = (bf16_t)u.w;
    r[4] = (bf16_t)v.x; r[5] = (bf16_t)v.y; r[6] = (bf16_t)v.z; r[7] = (bf16_t)v.w;
    return r;
}

// ---------------------------------------------------------------------------
// f32 -> bf16 bulk convert (weights, once per launch). n % 2048 == 0.
// ---------------------------------------------------------------------------
__global__ __launch_bounds__(256) void cvt_kernel(
    const float* __restrict__ src, bf16_t* __restrict__ dst, long n)
{
    long i = ((long)blockIdx.x * 256 + threadIdx.x) * 8;
    if (i < n) {
        float4 a = *(const float4*)(src + i);
        float4 b = *(const float4*)(src + i + 4);
        *(bf16x8*)(dst + i) = pack8(a, b);
    }
}

// ---------------------------------------------------------------------------
// Embedding + decoder-level rotary
// ---------------------------------------------------------------------------
__global__ __launch_bounds__(512) void embed_rope_kernel(
    const int* __restrict__ x, const float* __restrict__ tok_emb,
    const float* __restrict__ pos_emb, const float* __restrict__ inv_freq,
    const float* __restrict__ rbias, float* __restrict__ h, int S)
{
    const int row = blockIdx.x;      // b*S + s
    const int s = row % S;
    const int i = threadIdx.x;       // 0..511 pair index
    const int tok = x[row];
    const float* e = tok_emb + (size_t)tok * DD;
    const float* p = pos_emb + (size_t)s * DD;
    float a = e[2*i]   + p[2*i];
    float b = e[2*i+1] + p[2*i+1];
    float fr = (float)s * inv_freq[i] + rbias[(size_t)s * (DD/2) + i];
    float c = cosf(fr), sn = sinf(fr);
    h[(size_t)row*DD + 2*i]   = a*c - b*sn;
    h[(size_t)row*DD + 2*i+1] = a*sn + b*c;
}

// ---------------------------------------------------------------------------
// Per-head rotary in place; for K also emits zmult[bh][s] (scaled_zero table)
// ---------------------------------------------------------------------------
__global__ __launch_bounds__(512) void rope_head_kernel(
    float* __restrict__ t, const float* __restrict__ inv_freq,
    const float* __restrict__ rbias, const float* __restrict__ fptr,
    float* __restrict__ zmult, int S)
{
    const int row = blockIdx.x;      // b*S + s
    const int s = row % S;
    const int tid = threadIdx.x;
    const int hh = tid >> 5;         // 0..15
    const int i  = tid & 31;         // 0..31
    const size_t base = (size_t)row*DD + hh*HDIM;
    float a = t[base + 2*i];
    float b = t[base + 2*i + 1];
    float fr = (float)s * inv_freq[i] + rbias[(size_t)s * (HDIM/2) + i];
    float c = cosf(fr), sn = sinf(fr);
    float na = a*c - b*sn;
    float nb = a*sn + b*c;
    t[base + 2*i]     = na;
    t[base + 2*i + 1] = nb;
    if (zmult != nullptr && i == 0) {
        float f = fptr[0];
        float sp = (f > 20.f) ? f : log1pf(expf(f));
        float zf = fminf(fmaxf(sp, 1e-5f), 0.1f);
        int bb = row / S;
        zmult[(size_t)(bb*HEADS + hh)*S + s] = (na == 0.0f) ? zf : 1.0f;
    }
}

// ---------------------------------------------------------------------------
// RMSNorm with bf16 output
// ---------------------------------------------------------------------------
__global__ __launch_bounds__(256) void rmsnorm_kernel(
    const float* __restrict__ x, const float* __restrict__ w,
    bf16_t* __restrict__ y)
{
    const int row = blockIdx.x;
    const float* xr = x + (size_t)row * DD;
    float ss = 0.f;
    for (int j = threadIdx.x; j < DD; j += 256) { float v = xr[j]; ss += v*v; }
    for (int off = 32; off > 0; off >>= 1) ss += __shfl_down(ss, off, 64);
    __shared__ float r[4];
    if ((threadIdx.x & 63) == 0) r[threadIdx.x >> 6] = ss;
    __syncthreads();
    float tot = r[0] + r[1] + r[2] + r[3];
    float sc = rsqrtf(tot * (1.0f/(float)DD) + 1e-8f);
    for (int j = threadIdx.x; j < DD; j += 256)
        y[(size_t)row*DD + j] = (bf16_t)(xr[j] * sc * w[j]);
}

// ---------------------------------------------------------------------------
// bf16 MFMA GEMM, m97 structure: 128x128 tile, BK=64, linear LDS [128][64],
// global_load_lds 16B staging (no VALU in hot loop). A: MxK bf16, W: NxK bf16.
// Epilogue modes: 0 = f32 C [row][N]; 1 = bf16 Cb [row][N]; 2 = bf16 Vt
// [b][h][d][S]. bias/add1/add2 (f32) and relu fused.
// C/D frag: col=l&15, row=(l>>4)*4+r (m89/m91-verified).
// ---------------------------------------------------------------------------
__global__ __launch_bounds__(256) void gemm_bf(
    const bf16_t* __restrict__ A, const bf16_t* __restrict__ W,
    const float* __restrict__ bias, const float* __restrict__ add1,
    const float* __restrict__ add2, float* __restrict__ C,
    bf16_t* __restrict__ Cb,
    int M, int N, int K, int relu, int mode)
{
    __shared__ __align__(16) bf16_t As[128*64];
    __shared__ __align__(16) bf16_t Bs[128*64];
    const int tid = threadIdx.x;
    const int m0 = blockIdx.y * 128, n0 = blockIdx.x * 128;
    const int l = tid & 63, w = tid >> 6;
    const int wr = (w >> 1) * 64, wc = (w & 1) * 64;
    const int lr = l & 15, lk = (l >> 4) * 8;

    // staging: instruction j=w*4+it covers tile rows j*8 + (l>>3), cols (l&7)*8
    const int srow = l >> 3, scol = (l & 7) * 8;
    const bf16_t* Ag = A + (size_t)(m0 + w*32 + srow) * K + scol;
    const bf16_t* Wg = W + (size_t)(n0 + w*32 + srow) * K + scol;

    f32x4 z4 = {0.f, 0.f, 0.f, 0.f};
    f32x4 acc[4][4];
    #pragma unroll
    for (int i = 0; i < 4; ++i)
        #pragma unroll
        for (int j = 0; j < 4; ++j) acc[i][j] = z4;

    for (int k0 = 0; k0 < K; k0 += 64) {
        __syncthreads();                       // prior tile's ds_reads done
        #pragma unroll
        for (int it = 0; it < 4; ++it) {
            GLD16(Ag + (size_t)(it*8)*K + k0, As + (w*4 + it)*512);
            GLD16(Wg + (size_t)(it*8)*K + k0, Bs + (w*4 + it)*512);
        }
        __syncthreads();                       // drains vmcnt(0): tiles ready
        #pragma unroll
        for (int kk = 0; kk < 2; ++kk) {
            bf16x8 afr[4], bfr[4];
            #pragma unroll
            for (int i = 0; i < 4; ++i)
                afr[i] = *(const bf16x8*)&As[(wr + i*16 + lr)*64 + kk*32 + lk];
            #pragma unroll
            for (int j = 0; j < 4; ++j)
                bfr[j] = *(const bf16x8*)&Bs[(wc + j*16 + lr)*64 + kk*32 + lk];
            #pragma unroll
            for (int i = 0; i < 4; ++i)
                #pragma unroll
                for (int j = 0; j < 4; ++j)
                    acc[i][j] = MFMA16(afr[i], bfr[j], acc[i][j]);
        }
    }

    #pragma unroll
    for (int i = 0; i < 4; ++i) {
        #pragma unroll
        for (int j = 0; j < 4; ++j) {
            const int col  = n0 + wc + j*16 + lr;
            const int row0 = m0 + wr + i*16 + (l >> 4)*4;
            const float bv = bias ? bias[col] : 0.f;
            #pragma unroll
            for (int r2 = 0; r2 < 4; ++r2) {
                const int row = row0 + r2;
                float val = acc[i][j][r2] + bv;
                if (add1) val += add1[(size_t)row*N + col];
                if (add2) val += add2[(size_t)row*N + col];
                if (relu) val = fmaxf(val, 0.f);
                if (mode == 0) {
                    C[(size_t)row*N + col] = val;
                } else if (mode == 1) {
                    Cb[(size_t)row*N + col] = (bf16_t)val;
                } else {
                    const int bb = row >> 10, s = row & (SEQ - 1);
                    const int hh = col >> 6,  d = col & 63;
                    Cb[((size_t)(bb*HEADS + hh)*HDIM + d)*SEQ + s] = (bf16_t)val;
                }
            }
        }
    }
}

// ---------------------------------------------------------------------------
// Fallback logits GEMM when ws can't hold bf16 tok_emb: A bf16 (gload_lds),
// W f32 (reg-stage + cvt). C f32, no bias/add/relu.
// ---------------------------------------------------------------------------
__global__ __launch_bounds__(256) void gemm_bfw32(
    const bf16_t* __restrict__ A, const float* __restrict__ W,
    float* __restrict__ C, int M, int N, int K)
{
    __shared__ __align__(16) bf16_t As[128*64];
    __shared__ __align__(16) bf16_t Bs[128*64];
    const int tid = threadIdx.x;
    const int m0 = blockIdx.y * 128, n0 = blockIdx.x * 128;
    const int l = tid & 63, w = tid >> 6;
    const int wr = (w >> 1) * 64, wc = (w & 1) * 64;
    const int lr = l & 15, lk = (l >> 4) * 8;
    const int srow = l >> 3, scol = (l & 7) * 8;
    const bf16_t* Ag = A + (size_t)(m0 + w*32 + srow) * K + scol;
    const int r = tid >> 1, half = (tid & 1) * 32;
    const float* Wp = W + (size_t)(n0 + r) * K + half;

    f32x4 z4 = {0.f, 0.f, 0.f, 0.f};
    f32x4 acc[4][4];
    #pragma unroll
    for (int i = 0; i < 4; ++i)
        #pragma unroll
        for (int j = 0; j < 4; ++j) acc[i][j] = z4;

    for (int k0 = 0; k0 < K; k0 += 64) {
        float4 wv[8];
        #pragma unroll
        for (int j = 0; j < 8; ++j) wv[j] = *(const float4*)(Wp + k0 + 4*j);
        __syncthreads();
        #pragma unroll
        for (int it = 0; it < 4; ++it)
            GLD16(Ag + (size_t)(it*8)*K + k0, As + (w*4 + it)*512);
        #pragma unroll
        for (int j = 0; j < 4; ++j)
            *(bf16x8*)&Bs[r*64 + half + 8*j] = pack8(wv[2*j], wv[2*j+1]);
        __syncthreads();
        #pragma unroll
        for (int kk = 0; kk < 2; ++kk) {
            bf16x8 afr[4], bfr[4];
            #pragma unroll
            for (int i = 0; i < 4; ++i)
                afr[i] = *(const bf16x8*)&As[(wr + i*16 + lr)*64 + kk*32 + lk];
            #pragma unroll
            for (int j = 0; j < 4; ++j)
                bfr[j] = *(const bf16x8*)&Bs[(wc + j*16 + lr)*64 + kk*32 + lk];
            #pragma unroll
            for (int i = 0; i < 4; ++i)
                #pragma unroll
                for (int j = 0; j < 4; ++j)
                    acc[i][j] = MFMA16(afr[i], bfr[j], acc[i][j]);
        }
    }
    #pragma unroll
    for (int i = 0; i < 4; ++i)
        #pragma unroll
        for (int j = 0; j < 4; ++j) {
            const int col  = n0 + wc + j*16 + lr;
            const int row0 = m0 + wr + i*16 + (l >> 4)*4;
            #pragma unroll
            for (int r2 = 0; r2 < 4; ++r2)
                C[(size_t)(row0 + r2)*N + col] = acc[i][j][r2];
        }
}

// ---------------------------------------------------------------------------
// QK^T per (b,h): S_bf[bh][q][key] = (key<=q) ? dot*0.125*zmult[bh][key] : 0
// Masked entries are EXACT 0 and participate in softmax (reference multiplies
// scores by the causal mask; it does not use -inf).
// ---------------------------------------------------------------------------
__global__ __launch_bounds__(256) void qk_kernel(
    const float* __restrict__ q, const float* __restrict__ k,
    const float* __restrict__ zmult, bf16_t* __restrict__ Sout, int S)
{
    __shared__ __align__(16) bf16_t As[128][72];
    __shared__ __align__(16) bf16_t Bs[128][72];
    const int tid = threadIdx.x;
    const int bh = blockIdx.z;
    const int b = bh >> 4, hh = bh & 15;
    const int q0 = blockIdx.y * 128, c0 = blockIdx.x * 128;
    const int l = tid & 63, w = tid >> 6;
    const int wr = (w >> 1) * 64, wc = (w & 1) * 64;
    const int lr = l & 15, lk = (l >> 4) * 8;

    if (c0 > q0 + 127) {   // fully masked tile: write exact zeros
        #pragma unroll
        for (int i = 0; i < 4; ++i)
            #pragma unroll
            for (int j = 0; j < 4; ++j) {
                const int key  = c0 + wc + j*16 + lr;
                const int row0 = q0 + wr + i*16 + (l >> 4)*4;
                #pragma unroll
                for (int r2 = 0; r2 < 4; ++r2)
                    Sout[((size_t)bh*S + row0 + r2)*S + key] = (bf16_t)0.f;
            }
        return;
    }

    const int r = tid >> 1, half = (tid & 1) * 32;
    {
        const float* qp = q + ((size_t)(b*S + q0 + r))*DD + hh*HDIM + half;
        const float* kp = k + ((size_t)(b*S + c0 + r))*DD + hh*HDIM + half;
        float4 av[8], wv[8];
        #pragma unroll
        for (int j = 0; j < 8; ++j) {
            av[j] = *(const float4*)(qp + 4*j);
            wv[j] = *(const float4*)(kp + 4*j);
        }
        #pragma unroll
        for (int j = 0; j < 4; ++j) {
            *(bf16x8*)&As[r][half + 8*j] = pack8(av[2*j], av[2*j+1]);
            *(bf16x8*)&Bs[r][half + 8*j] = pack8(wv[2*j], wv[2*j+1]);
        }
        __syncthreads();
    }

    f32x4 z4 = {0.f, 0.f, 0.f, 0.f};
    f32x4 acc[4][4];
    #pragma unroll
    for (int i = 0; i < 4; ++i)
        #pragma unroll
        for (int j = 0; j < 4; ++j) acc[i][j] = z4;

    #pragma unroll
    for (int kk = 0; kk < 2; ++kk) {
        bf16x8 afr[4], bfr[4];
        #pragma unroll
        for (int i = 0; i < 4; ++i)
            afr[i] = *(const bf16x8*)&As[wr + i*16 + lr][kk*32 + lk];
        #pragma unroll
        for (int j = 0; j < 4; ++j)
            bfr[j] = *(const bf16x8*)&Bs[wc + j*16 + lr][kk*32 + lk];
        #pragma unroll
        for (int i = 0; i < 4; ++i)
            #pragma unroll
            for (int j = 0; j < 4; ++j)
                acc[i][j] = MFMA16(afr[i], bfr[j], acc[i][j]);
    }

    #pragma unroll
    for (int i = 0; i < 4; ++i) {
        #pragma unroll
        for (int j = 0; j < 4; ++j) {
            const int key  = c0 + wc + j*16 + lr;
            const int row0 = q0 + wr + i*16 + (l >> 4)*4;
            const float zm = zmult[(size_t)bh*S + key];
            #pragma unroll
            for (int r2 = 0; r2 < 4; ++r2) {
                const int qi = row0 + r2;
                float val = acc[i][j][r2] * 0.125f;   // HD^-0.5
                val = (key <= qi) ? val * zm : 0.f;
                Sout[((size_t)bh*S + qi)*S + key] = (bf16_t)val;
            }
        }
    }
}

// ---------------------------------------------------------------------------
// Row softmax, in place over bf16 rows of length 1024. f32 internally.
// ---------------------------------------------------------------------------
__global__ __launch_bounds__(256) void softmax_rows(bf16_t* __restrict__ Sbuf)
{
    const size_t row = blockIdx.x;
    bf16_t* p = Sbuf + row * SEQ;
    const int t = threadIdx.x;
    bf16x4v x = *(const bf16x4v*)(p + t*4);
    float v0 = (float)x[0], v1 = (float)x[1], v2 = (float)x[2], v3 = (float)x[3];

    float m = fmaxf(fmaxf(v0, v1), fmaxf(v2, v3));
    for (int off = 32; off > 0; off >>= 1) m = fmaxf(m, __shfl_xor(m, off, 64));
    __shared__ float rm[4], rs[4];
    if ((t & 63) == 0) rm[t >> 6] = m;
    __syncthreads();
    m = fmaxf(fmaxf(rm[0], rm[1]), fmaxf(rm[2], rm[3]));

    float e0 = expf(v0 - m), e1 = expf(v1 - m), e2 = expf(v2 - m), e3 = expf(v3 - m);
    float s = e0 + e1 + e2 + e3;
    for (int off = 32; off > 0; off >>= 1) s += __shfl_xor(s, off, 64);
    if ((t & 63) == 0) rs[t >> 6] = s;
    __syncthreads();
    const float inv = 1.0f / (rs[0] + rs[1] + rs[2] + rs[3]);

    bf16x4v o;
    o[0] = (bf16_t)(e0 * inv); o[1] = (bf16_t)(e1 * inv);
    o[2] = (bf16_t)(e2 * inv); o[3] = (bf16_t)(e3 * inv);
    *(bf16x4v*)(p + t*4) = o;
}

// ---------------------------------------------------------------------------
// PV per (b,h): O[q][d] = sum_k P[q][k] * Vt[d][k]. Output bf16 [row][DD].
// ---------------------------------------------------------------------------
__global__ __launch_bounds__(256) void pv_kernel(
    const bf16_t* __restrict__ P, const bf16_t* __restrict__ Vt,
    bf16_t* __restrict__ O, int S)
{
    __shared__ __align__(16) bf16_t As[128][72];
    __shared__ __align__(16) bf16_t Bs[64][72];
    const int tid = threadIdx.x;
    const int bh = blockIdx.z, b = bh >> 4, hh = bh & 15;
    const int q0 = blockIdx.y * 128;
    const int l = tid & 63, w = tid >> 6;
    const int wr = w * 32;
    const int lr = l & 15, lk = (l >> 4) * 8;

    const bf16_t* Pp = P  + ((size_t)bh * S + q0) * S;
    const bf16_t* Vp = Vt + ((size_t)bh * HDIM) * S;

    const int ra = tid >> 1, ha = (tid & 1) * 32;
    const int rb = tid >> 2, hb = (tid & 3) * 16;

    f32x4 z4 = {0.f, 0.f, 0.f, 0.f};
    f32x4 acc[2][4];
    #pragma unroll
    for (int i = 0; i < 2; ++i)
        #pragma unroll
        for (int j = 0; j < 4; ++j) acc[i][j] = z4;

    for (int k0 = 0; k0 < S; k0 += 64) {
        bf16x8 a0 = *(const bf16x8*)(Pp + (size_t)ra*S + k0 + ha + 0);
        bf16x8 a1 = *(const bf16x8*)(Pp + (size_t)ra*S + k0 + ha + 8);
        bf16x8 a2 = *(const bf16x8*)(Pp + (size_t)ra*S + k0 + ha + 16);
        bf16x8 a3 = *(const bf16x8*)(Pp + (size_t)ra*S + k0 + ha + 24);
        bf16x8 b0 = *(const bf16x8*)(Vp + (size_t)rb*S + k0 + hb + 0);
        bf16x8 b1 = *(const bf16x8*)(Vp + (size_t)rb*S + k0 + hb + 8);
        __syncthreads();
        *(bf16x8*)&As[ra][ha + 0]  = a0;
        *(bf16x8*)&As[ra][ha + 8]  = a1;
        *(bf16x8*)&As[ra][ha + 16] = a2;
        *(bf16x8*)&As[ra][ha + 24] = a3;
        *(bf16x8*)&Bs[rb][hb + 0]  = b0;
        *(bf16x8*)&Bs[rb][hb + 8]  = b1;
        __syncthreads();
        #pragma unroll
        for (int kk = 0; kk < 2; ++kk) {
            bf16x8 afr[2], bfr[4];
            #pragma unroll
            for (int i = 0; i < 2; ++i)
                afr[i] = *(const bf16x8*)&As[wr + i*16 + lr][kk*32 + lk];
            #pragma unroll
            for (int j = 0; j < 4; ++j)
                bfr[j] = *(const bf16x8*)&Bs[j*16 + lr][kk*32 + lk];
            #pragma unroll
            for (int i = 0; i < 2; ++i)
                #pragma unroll
                for (int j = 0; j < 4; ++j)
                    acc[i][j] = MFMA16(afr[i], bfr[j], acc[i][j]);
        }
    }

    #pragma unroll
    for (int i = 0; i < 2; ++i) {
        #pragma unroll
        for (int j = 0; j < 4; ++j) {
            const int d    = j*16 + lr;
            const int row0 = q0 + wr + i*16 + (l >> 4)*4;
            #pragma unroll
            for (int r2 = 0; r2 < 4; ++r2)
                O[((size_t)(b*S + row0 + r2))*DD + hh*HDIM + d] = (bf16_t)acc[i][j][r2];
        }
    }
}

// ---------------------------------------------------------------------------
extern "C" void kernel_launch(void* const* d_in, const int* in_sizes, int n_in,
                              void* d_out, int out_size, void* d_ws, size_t ws_size,
                              hipStream_t stream)
{
    const int S = SEQ;
    const int B = in_sizes[0] / S;     // 2
    const int M = B * S;               // 2048
    const int BH = B * HEADS;          // 32

    const int*   x       = (const int*)  d_in[0];
    const float* tok_emb = (const float*)d_in[2];
    const float* pos_emb = (const float*)d_in[3];
    const float* rif     = (const float*)d_in[4];
    const float* rbias   = (const float*)d_in[5];
    const float* brif    = (const float*)d_in[6];
    const float* bbias   = (const float*)d_in[7];
    const float* lna     = (const float*)d_in[8];
    const float* qw      = (const float*)d_in[9];
    const float* qb      = (const float*)d_in[10];
    const float* kw      = (const float*)d_in[11];
    const float* vw      = (const float*)d_in[12];
    const float* vbias   = (const float*)d_in[13];
    const float* ow      = (const float*)d_in[14];
    const float* ob      = (const float*)d_in[15];
    const float* factor  = (const float*)d_in[16];
    const float* lnc     = (const float*)d_in[17];
    const float* w1      = (const float*)d_in[18];
    const float* b1      = (const float*)d_in[19];
    const float* w2      = (const float*)d_in[20];
    const float* b2      = (const float*)d_in[21];
    const float* lnd     = (const float*)d_in[22];

    char* ob_ = (char*)d_out;
    const size_t MiB = 1024*1024;
    // d_out scratch map (all dead by the time the logits GEMM overwrites out):
    float*  h      = (float*)(ob_ + 0*MiB);      // 8 MiB
    float*  h2     = (float*)(ob_ + 8*MiB);      // 8 MiB
    float*  q      = (float*)(ob_ + 16*MiB);     // 8 MiB
    float*  k      = (float*)(ob_ + 24*MiB);     // 8 MiB
    bf16_t* vt     = (bf16_t*)(ob_ + 32*MiB);    // 4 MiB  Vt[b][h][d][S]
    bf16_t* attno  = (bf16_t*)(ob_ + 36*MiB);    // 4 MiB
    bf16_t* m1     = (bf16_t*)(ob_ + 40*MiB);    // 16 MiB
    float*  zmult  = (float*)(ob_ + 56*MiB);     // 128 KiB
    bf16_t* qw_bf  = (bf16_t*)(ob_ + 64*MiB);    // 8 MiB (4 layers)
    bf16_t* kw_bf  = (bf16_t*)(ob_ + 72*MiB);
    bf16_t* vw_bf  = (bf16_t*)(ob_ + 80*MiB);
    bf16_t* ow_bf  = (bf16_t*)(ob_ + 88*MiB);
    bf16_t* w1_bf  = (bf16_t*)(ob_ + 96*MiB);    // 32 MiB
    bf16_t* w2_bf  = (bf16_t*)(ob_ + 128*MiB);   // 32 MiB
    bf16_t* Sbuf   = (bf16_t*)(ob_ + 160*MiB);   // 64 MiB -> ends 224 MiB < 250 MiB

    // d_ws: hn_bf (4 MiB) always; tok_emb bf16 (62.5 MiB) if it fits.
    bf16_t* hn     = (bf16_t*)d_ws;
    bf16_t* temb_bf = (bf16_t*)((char*)d_ws + 4*MiB);
    const bool big_ws = ws_size >= (size_t)(70*MiB);

    const long NW_D = (long)NLAYER * DD * DD;       // 4,194,304
    const long NW_F = (long)NLAYER * FFDIM * DD;    // 16,777,216
    const long NW_E = (long)NVOCAB * DD;            // 32,768,000
    cvt_kernel<<<NW_D/2048, 256, 0, stream>>>(qw, qw_bf, NW_D);
    cvt_kernel<<<NW_D/2048, 256, 0, stream>>>(kw, kw_bf, NW_D);
    cvt_kernel<<<NW_D/2048, 256, 0, stream>>>(vw, vw_bf, NW_D);
    cvt_kernel<<<NW_D/2048, 256, 0, stream>>>(ow, ow_bf, NW_D);
    cvt_kernel<<<NW_F/2048, 256, 0, stream>>>(w1, w1_bf, NW_F);
    cvt_kernel<<<NW_F/2048, 256, 0, stream>>>(w2, w2_bf, NW_F);
    if (big_ws)
        cvt_kernel<<<(NW_E+2047)/2048, 256, 0, stream>>>(tok_emb, temb_bf, NW_E);

    dim3 gD(DD/128,     M/128);
    dim3 gF(FFDIM/128,  M/128);
    dim3 gV(NVOCAB/128, M/128);
    dim3 gQK(S/128, S/128, BH);
    dim3 gPV(1, S/128, BH);

    embed_rope_kernel<<<M, 512, 0, stream>>>(x, tok_emb, pos_emb, rif, rbias, h, S);

    for (int l = 0; l < NLAYER; ++l) {
        const size_t wo = (size_t)l * DD * DD;
        const size_t fo = (size_t)l * FFDIM * DD;
        rmsnorm_kernel<<<M, 256, 0, stream>>>(h, lna + l*DD, hn);
        gemm_bf<<<gD, 256, 0, stream>>>(hn, qw_bf + wo, qb + l*DD, nullptr, nullptr, q, nullptr, M, DD, DD, 0, 0);
        gemm_bf<<<gD, 256, 0, stream>>>(hn, kw_bf + wo, nullptr,   nullptr, nullptr, k, nullptr, M, DD, DD, 0, 0);
        gemm_bf<<<gD, 256, 0, stream>>>(hn, vw_bf + wo, vbias + l*DD, nullptr, nullptr, nullptr, vt, M, DD, DD, 0, 2);
        rope_head_kernel<<<M, 512, 0, stream>>>(q, brif, bbias, nullptr, nullptr, S);
        rope_head_kernel<<<M, 512, 0, stream>>>(k, brif, bbias, factor + l, zmult, S);
        qk_kernel<<<gQK, 256, 0, stream>>>(q, k, zmult, Sbuf, S);
        softmax_rows<<<BH * S, 256, 0, stream>>>(Sbuf);
        pv_kernel<<<gPV, 256, 0, stream>>>(Sbuf, vt, attno, S);
        // h2 = attno @ ow^T + ob + h
        gemm_bf<<<gD, 256, 0, stream>>>(attno, ow_bf + wo, ob + l*DD, h, nullptr, h2, nullptr, M, DD, DD, 0, 0);
        rmsnorm_kernel<<<M, 256, 0, stream>>>(h2, lnc + l*DD, hn);
        gemm_bf<<<gF, 256, 0, stream>>>(hn, w1_bf + fo, b1 + l*FFDIM, nullptr, nullptr, nullptr, m1, M, FFDIM, DD, 1, 1);
        // h_new = m1 @ w2^T + b2 + h2 + h   (== 2*h_old + attn + mlp)
        gemm_bf<<<gD, 256, 0, stream>>>(m1, w2_bf + fo, b2 + l*DD, h2, h, h, nullptr, M, DD, FFDIM, 0, 0);
    }

    rmsnorm_kernel<<<M, 256, 0, stream>>>(h, lnd, hn);
    if (big_ws)
        gemm_bf<<<gV, 256, 0, stream>>>(hn, temb_bf, nullptr, nullptr, nullptr, (float*)d_out, nullptr, M, NVOCAB, DD, 0, 0);
    else
        gemm_bfw32<<<gV, 256, 0, stream>>>(hn, tok_emb, (float*)d_out, M, NVOCAB, DD);
}

// Round 5
// 1682.758 us; speedup vs baseline: 4.8323x; 1.2461x over previous
//
#include <hip/hip_runtime.h>
#include <hip/hip_bf16.h>

#define DD 1024
#define HEADS 16
#define HDIM 64
#define NLAYER 4
#define FFDIM 4096
#define NVOCAB 32000
#define SEQ 1024

typedef __bf16 bf16_t;
typedef __bf16 bf16x8 __attribute__((ext_vector_type(8)));
typedef float f32x4 __attribute__((ext_vector_type(4)));

#define MFMA16(a, b, c) __builtin_amdgcn_mfma_f32_16x16x32_bf16((a), (b), (c), 0, 0, 0)

// async global->LDS, 16B per lane, dest = wave-uniform base + lane*16
#define GLD16(gp, lp) \
    __builtin_amdgcn_global_load_lds( \
        (const __attribute__((address_space(1))) void*)(gp), \
        (__attribute__((address_space(3))) void*)(lp), 16, 0, 0)

static __device__ __forceinline__ bf16x8 pack8(float4 u, float4 v) {
    bf16x8 r;
    r[0] = (bf16_t)u.x; r[1] = (bf16_t)u.y; r[2] = (bf16_t)u.z; r[3] = (bf16_t)u.w;
    r[4] = (bf16_t)v.x; r[5] = (bf16_t)v.y; r[6] = (bf16_t)v.z; r[7] = (bf16_t)v.w;
    return r;
}

// ---------------------------------------------------------------------------
// f32 -> bf16 bulk convert (weights, once per launch). n % 2048 == 0.
// ---------------------------------------------------------------------------
__global__ __launch_bounds__(256) void cvt_kernel(
    const float* __restrict__ src, bf16_t* __restrict__ dst, long n)
{
    long i = ((long)blockIdx.x * 256 + threadIdx.x) * 8;
    if (i < n) {
        float4 a = *(const float4*)(src + i);
        float4 b = *(const float4*)(src + i + 4);
        *(bf16x8*)(dst + i) = pack8(a, b);
    }
}

// ---------------------------------------------------------------------------
// Head-rope cos/sin tables: [S][32]
// ---------------------------------------------------------------------------
__global__ __launch_bounds__(256) void ropetab_kernel(
    const float* __restrict__ inv_freq, const float* __restrict__ rbias,
    float* __restrict__ ctab, float* __restrict__ stab)
{
    int idx = blockIdx.x * 256 + threadIdx.x;     // s*32 + i
    int s = idx >> 5, i = idx & 31;
    float fr = (float)s * inv_freq[i] + rbias[idx];
    ctab[idx] = cosf(fr);
    stab[idx] = sinf(fr);
}

// ---------------------------------------------------------------------------
// Embedding + decoder-level rotary
// ---------------------------------------------------------------------------
__global__ __launch_bounds__(512) void embed_rope_kernel(
    const int* __restrict__ x, const float* __restrict__ tok_emb,
    const float* __restrict__ pos_emb, const float* __restrict__ inv_freq,
    const float* __restrict__ rbias, float* __restrict__ h, int S)
{
    const int row = blockIdx.x;      // b*S + s
    const int s = row % S;
    const int i = threadIdx.x;       // 0..511 pair index
    const int tok = x[row];
    const float* e = tok_emb + (size_t)tok * DD;
    const float* p = pos_emb + (size_t)s * DD;
    float a = e[2*i]   + p[2*i];
    float b = e[2*i+1] + p[2*i+1];
    float fr = (float)s * inv_freq[i] + rbias[(size_t)s * (DD/2) + i];
    float c = cosf(fr), sn = sinf(fr);
    h[(size_t)row*DD + 2*i]   = a*c - b*sn;
    h[(size_t)row*DD + 2*i+1] = a*sn + b*c;
}

// ---------------------------------------------------------------------------
// RMSNorm with bf16 output
// ---------------------------------------------------------------------------
__global__ __launch_bounds__(256) void rmsnorm_kernel(
    const float* __restrict__ x, const float* __restrict__ w,
    bf16_t* __restrict__ y)
{
    const int row = blockIdx.x;
    const float* xr = x + (size_t)row * DD;
    float ss = 0.f;
    for (int j = threadIdx.x; j < DD; j += 256) { float v = xr[j]; ss += v*v; }
    for (int off = 32; off > 0; off >>= 1) ss += __shfl_down(ss, off, 64);
    __shared__ float r[4];
    if ((threadIdx.x & 63) == 0) r[threadIdx.x >> 6] = ss;
    __syncthreads();
    float tot = r[0] + r[1] + r[2] + r[3];
    float sc = rsqrtf(tot * (1.0f/(float)DD) + 1e-8f);
    for (int j = threadIdx.x; j < DD; j += 256)
        y[(size_t)row*DD + j] = (bf16_t)(xr[j] * sc * w[j]);
}

// ---------------------------------------------------------------------------
// Generic bf16 MFMA GEMM (m97 structure). A: MxK bf16, W: NxK bf16.
// modes: 0 = f32 C; 1 = bf16 Cb. swz=1: n-major XCD-chunked block swizzle.
// ---------------------------------------------------------------------------
__global__ __launch_bounds__(256) void gemm_bf(
    const bf16_t* __restrict__ A, const bf16_t* __restrict__ W,
    const float* __restrict__ bias, const float* __restrict__ add1,
    const float* __restrict__ add2, float* __restrict__ C,
    bf16_t* __restrict__ Cb,
    int M, int N, int K, int relu, int mode, int swz)
{
    __shared__ __align__(16) bf16_t As[128*64];
    __shared__ __align__(16) bf16_t Bs[128*64];
    const int tid = threadIdx.x;
    int bx = blockIdx.x, by = blockIdx.y;
    if (swz) {
        const int nbx = gridDim.x, nby = gridDim.y;
        const int nwg = nbx * nby;             // divisible by 8
        const int lin = by * nbx + bx;
        const int wg  = (lin & 7) * (nwg >> 3) + (lin >> 3);
        bx = wg / nby;                         // n-major: 16 same-n blocks adjacent
        by = wg % nby;
    }
    const int m0 = by * 128, n0 = bx * 128;
    const int l = tid & 63, w = tid >> 6;
    const int wr = (w >> 1) * 64, wc = (w & 1) * 64;
    const int lr = l & 15, lk = (l >> 4) * 8;

    const int srow = l >> 3, scol = (l & 7) * 8;
    const bf16_t* Ag = A + (size_t)(m0 + w*32 + srow) * K + scol;
    const bf16_t* Wg = W + (size_t)(n0 + w*32 + srow) * K + scol;

    f32x4 z4 = {0.f, 0.f, 0.f, 0.f};
    f32x4 acc[4][4];
    #pragma unroll
    for (int i = 0; i < 4; ++i)
        #pragma unroll
        for (int j = 0; j < 4; ++j) acc[i][j] = z4;

    for (int k0 = 0; k0 < K; k0 += 64) {
        __syncthreads();
        #pragma unroll
        for (int it = 0; it < 4; ++it) {
            GLD16(Ag + (size_t)(it*8)*K + k0, As + (w*4 + it)*512);
            GLD16(Wg + (size_t)(it*8)*K + k0, Bs + (w*4 + it)*512);
        }
        __syncthreads();
        #pragma unroll
        for (int kk = 0; kk < 2; ++kk) {
            bf16x8 afr[4], bfr[4];
            #pragma unroll
            for (int i = 0; i < 4; ++i)
                afr[i] = *(const bf16x8*)&As[(wr + i*16 + lr)*64 + kk*32 + lk];
            #pragma unroll
            for (int j = 0; j < 4; ++j)
                bfr[j] = *(const bf16x8*)&Bs[(wc + j*16 + lr)*64 + kk*32 + lk];
            #pragma unroll
            for (int i = 0; i < 4; ++i)
                #pragma unroll
                for (int j = 0; j < 4; ++j)
                    acc[i][j] = MFMA16(afr[i], bfr[j], acc[i][j]);
        }
    }

    #pragma unroll
    for (int i = 0; i < 4; ++i) {
        #pragma unroll
        for (int j = 0; j < 4; ++j) {
            const int col  = n0 + wc + j*16 + lr;
            const int row0 = m0 + wr + i*16 + (l >> 4)*4;
            const float bv = bias ? bias[col] : 0.f;
            #pragma unroll
            for (int r2 = 0; r2 < 4; ++r2) {
                const int row = row0 + r2;
                float val = acc[i][j][r2] + bv;
                if (add1) val += add1[(size_t)row*N + col];
                if (add2) val += add2[(size_t)row*N + col];
                if (relu) val = fmaxf(val, 0.f);
                if (mode == 0) C[(size_t)row*N + col] = val;
                else           Cb[(size_t)row*N + col] = (bf16_t)val;
            }
        }
    }
}

// ---------------------------------------------------------------------------
// Fallback logits GEMM (A bf16 via gload_lds, W f32 reg-staged).
// ---------------------------------------------------------------------------
__global__ __launch_bounds__(256) void gemm_bfw32(
    const bf16_t* __restrict__ A, const float* __restrict__ W,
    float* __restrict__ C, int M, int N, int K)
{
    __shared__ __align__(16) bf16_t As[128*64];
    __shared__ __align__(16) bf16_t Bs[128*64];
    const int tid = threadIdx.x;
    const int m0 = blockIdx.y * 128, n0 = blockIdx.x * 128;
    const int l = tid & 63, w = tid >> 6;
    const int wr = (w >> 1) * 64, wc = (w & 1) * 64;
    const int lr = l & 15, lk = (l >> 4) * 8;
    const int srow = l >> 3, scol = (l & 7) * 8;
    const bf16_t* Ag = A + (size_t)(m0 + w*32 + srow) * K + scol;
    const int r = tid >> 1, half = (tid & 1) * 32;
    const float* Wp = W + (size_t)(n0 + r) * K + half;

    f32x4 z4 = {0.f, 0.f, 0.f, 0.f};
    f32x4 acc[4][4];
    #pragma unroll
    for (int i = 0; i < 4; ++i)
        #pragma unroll
        for (int j = 0; j < 4; ++j) acc[i][j] = z4;

    for (int k0 = 0; k0 < K; k0 += 64) {
        float4 wv[8];
        #pragma unroll
        for (int j = 0; j < 8; ++j) wv[j] = *(const float4*)(Wp + k0 + 4*j);
        __syncthreads();
        #pragma unroll
        for (int it = 0; it < 4; ++it)
            GLD16(Ag + (size_t)(it*8)*K + k0, As + (w*4 + it)*512);
        #pragma unroll
        for (int j = 0; j < 4; ++j)
            *(bf16x8*)&Bs[r*64 + half + 8*j] = pack8(wv[2*j], wv[2*j+1]);
        __syncthreads();
        #pragma unroll
        for (int kk = 0; kk < 2; ++kk) {
            bf16x8 afr[4], bfr[4];
            #pragma unroll
            for (int i = 0; i < 4; ++i)
                afr[i] = *(const bf16x8*)&As[(wr + i*16 + lr)*64 + kk*32 + lk];
            #pragma unroll
            for (int j = 0; j < 4; ++j)
                bfr[j] = *(const bf16x8*)&Bs[(wc + j*16 + lr)*64 + kk*32 + lk];
            #pragma unroll
            for (int i = 0; i < 4; ++i)
                #pragma unroll
                for (int j = 0; j < 4; ++j)
                    acc[i][j] = MFMA16(afr[i], bfr[j], acc[i][j]);
        }
    }
    #pragma unroll
    for (int i = 0; i < 4; ++i)
        #pragma unroll
        for (int j = 0; j < 4; ++j) {
            const int col  = n0 + wc + j*16 + lr;
            const int row0 = m0 + wr + i*16 + (l >> 4)*4;
            #pragma unroll
            for (int r2 = 0; r2 < 4; ++r2)
                C[(size_t)(row0 + r2)*N + col] = acc[i][j][r2];
        }
}

// ---------------------------------------------------------------------------
// Fused QKV GEMM (M x 3072): seg 0=q (rope, ->qbf), 1=k (rope, ->kbf, zmult),
// 2=v (->Vt[b][h][d][S]). Rope pairs = adjacent cols = shfl_xor(val,1).
// ---------------------------------------------------------------------------
__global__ __launch_bounds__(256) void qkv_gemm(
    const bf16_t* __restrict__ A, const bf16_t* __restrict__ Wq,
    const bf16_t* __restrict__ Wk, const bf16_t* __restrict__ Wv,
    const float* __restrict__ qb, const float* __restrict__ vbias,
    const float* __restrict__ ctab, const float* __restrict__ stab,
    const float* __restrict__ fptr,
    bf16_t* __restrict__ qbf, bf16_t* __restrict__ kbf,
    bf16_t* __restrict__ vt, float* __restrict__ zmult, int S)
{
    __shared__ __align__(16) bf16_t As[128*64];
    __shared__ __align__(16) bf16_t Bs[128*64];
    const int tid = threadIdx.x;
    const int seg = blockIdx.x >> 3;              // 0=q 1=k 2=v
    const int n0  = (blockIdx.x & 7) * 128;       // col within segment
    const int m0  = blockIdx.y * 128;
    const bf16_t* W = (seg == 0) ? Wq : (seg == 1) ? Wk : Wv;
    const int K = DD;
    const int l = tid & 63, w = tid >> 6;
    const int wr = (w >> 1) * 64, wc = (w & 1) * 64;
    const int lr = l & 15, lk = (l >> 4) * 8;

    const int srow = l >> 3, scol = (l & 7) * 8;
    const bf16_t* Ag = A + (size_t)(m0 + w*32 + srow) * K + scol;
    const bf16_t* Wg = W + (size_t)(n0 + w*32 + srow) * K + scol;

    f32x4 z4 = {0.f, 0.f, 0.f, 0.f};
    f32x4 acc[4][4];
    #pragma unroll
    for (int i = 0; i < 4; ++i)
        #pragma unroll
        for (int j = 0; j < 4; ++j) acc[i][j] = z4;

    for (int k0 = 0; k0 < K; k0 += 64) {
        __syncthreads();
        #pragma unroll
        for (int it = 0; it < 4; ++it) {
            GLD16(Ag + (size_t)(it*8)*K + k0, As + (w*4 + it)*512);
            GLD16(Wg + (size_t)(it*8)*K + k0, Bs + (w*4 + it)*512);
        }
        __syncthreads();
        #pragma unroll
        for (int kk = 0; kk < 2; ++kk) {
            bf16x8 afr[4], bfr[4];
            #pragma unroll
            for (int i = 0; i < 4; ++i)
                afr[i] = *(const bf16x8*)&As[(wr + i*16 + lr)*64 + kk*32 + lk];
            #pragma unroll
            for (int j = 0; j < 4; ++j)
                bfr[j] = *(const bf16x8*)&Bs[(wc + j*16 + lr)*64 + kk*32 + lk];
            #pragma unroll
            for (int i = 0; i < 4; ++i)
                #pragma unroll
                for (int j = 0; j < 4; ++j)
                    acc[i][j] = MFMA16(afr[i], bfr[j], acc[i][j]);
        }
    }

    float zf = 0.f;
    if (seg == 1) {
        float f = fptr[0];
        float sp = (f > 20.f) ? f : log1pf(expf(f));
        zf = fminf(fmaxf(sp, 1e-5f), 0.1f);
    }

    #pragma unroll
    for (int i = 0; i < 4; ++i) {
        #pragma unroll
        for (int j = 0; j < 4; ++j) {
            const int col = n0 + wc + j*16 + lr;          // 0..1023 within seg
            const float bv = (seg == 0) ? qb[col] : (seg == 2) ? vbias[col] : 0.f;
            const int d  = col & 63;
            const int hh = col >> 6;
            const int pi = d >> 1;
            #pragma unroll
            for (int r2 = 0; r2 < 4; ++r2) {
                const int row = m0 + wr + i*16 + (l >> 4)*4 + r2;
                const int s  = row & (SEQ - 1);
                const int bb = row >> 10;
                float val = acc[i][j][r2] + bv;
                if (seg < 2) {
                    // rope: pair (even,odd) across lanes lr, lr^1
                    float partner = __shfl_xor(val, 1, 64);
                    float c  = ctab[s*32 + pi];
                    float sn = stab[s*32 + pi];
                    float out = ((d & 1) == 0) ? (val*c - partner*sn)
                                               : (partner*sn*0.f + partner*c*0.f + partner* sn + val*c); // placeholder
                    // correct odd: a=partner, b=val -> rb = a*sn + b*c
                    out = ((d & 1) == 0) ? (val*c - partner*sn)
                                         : (partner*sn + val*c);
                    if (seg == 0) {
                        qbf[(size_t)row*DD + col] = (bf16_t)out;
                    } else {
                        kbf[(size_t)row*DD + col] = (bf16_t)out;
                        if (d == 0)
                            zmult[(size_t)(bb*HEADS + hh)*S + s] =
                                (out == 0.0f) ? zf : 1.0f;
                    }
                } else {
                    vt[((size_t)(bb*HEADS + hh)*HDIM + d)*SEQ + s] = (bf16_t)val;
                }
            }
        }
    }
}

// ---------------------------------------------------------------------------
// QK^T per (b,h): Sout[bh][q][key] = (key<=q) ? dot*0.125*zmult : 0  (bf16)
// Also writes per-tile row maxes: tmax[(bh*S+q)*8 + keytile].
// ---------------------------------------------------------------------------
__global__ __launch_bounds__(256) void qk_kernel(
    const bf16_t* __restrict__ qbf, const bf16_t* __restrict__ kbf,
    const float* __restrict__ zmult, bf16_t* __restrict__ Sout,
    float* __restrict__ tmax, int S)
{
    __shared__ __align__(16) bf16_t As[128*64];
    __shared__ __align__(16) bf16_t Bs[128*64];
    __shared__ float tm[128][2];
    const int tid = threadIdx.x;
    const int bh = blockIdx.z;
    const int b = bh >> 4, hh = bh & 15;
    const int q0 = blockIdx.y * 128, c0 = blockIdx.x * 128;
    const int l = tid & 63, w = tid >> 6;
    const int wr = (w >> 1) * 64, wc = (w & 1) * 64;
    const int lr = l & 15, lk = (l >> 4) * 8;

    if (c0 > q0 + 127) {   // fully masked tile: zeros + tmax 0
        #pragma unroll
        for (int i = 0; i < 4; ++i)
            #pragma unroll
            for (int j = 0; j < 4; ++j) {
                const int key  = c0 + wc + j*16 + lr;
                const int row0 = q0 + wr + i*16 + (l >> 4)*4;
                #pragma unroll
                for (int r2 = 0; r2 < 4; ++r2)
                    Sout[((size_t)bh*S + row0 + r2)*S + key] = (bf16_t)0.f;
            }
        if (tid < 128)
            tmax[((size_t)bh*S + q0 + tid)*8 + (c0 >> 7)] = 0.f;
        return;
    }

    const int srow = l >> 3, scol = (l & 7) * 8;
    {
        const bf16_t* Ag = qbf + (size_t)(b*S + q0 + w*32 + srow)*DD + hh*HDIM + scol;
        const bf16_t* Bg = kbf + (size_t)(b*S + c0 + w*32 + srow)*DD + hh*HDIM + scol;
        #pragma unroll
        for (int it = 0; it < 4; ++it) {
            GLD16(Ag + (size_t)(it*8)*DD, As + (w*4 + it)*512);
            GLD16(Bg + (size_t)(it*8)*DD, Bs + (w*4 + it)*512);
        }
        __syncthreads();
    }

    f32x4 z4 = {0.f, 0.f, 0.f, 0.f};
    f32x4 acc[4][4];
    #pragma unroll
    for (int i = 0; i < 4; ++i)
        #pragma unroll
        for (int j = 0; j < 4; ++j) acc[i][j] = z4;

    #pragma unroll
    for (int kk = 0; kk < 2; ++kk) {
        bf16x8 afr[4], bfr[4];
        #pragma unroll
        for (int i = 0; i < 4; ++i)
            afr[i] = *(const bf16x8*)&As[(wr + i*16 + lr)*64 + kk*32 + lk];
        #pragma unroll
        for (int j = 0; j < 4; ++j)
            bfr[j] = *(const bf16x8*)&Bs[(wc + j*16 + lr)*64 + kk*32 + lk];
        #pragma unroll
        for (int i = 0; i < 4; ++i)
            #pragma unroll
            for (int j = 0; j < 4; ++j)
                acc[i][j] = MFMA16(afr[i], bfr[j], acc[i][j]);
    }

    #pragma unroll
    for (int i = 0; i < 4; ++i) {
        float rmax[4] = {-3.0e38f, -3.0e38f, -3.0e38f, -3.0e38f};
        #pragma unroll
        for (int j = 0; j < 4; ++j) {
            const int key = c0 + wc + j*16 + lr;
            const float zm = zmult[(size_t)bh*S + key];
            const int row0 = q0 + wr + i*16 + (l >> 4)*4;
            #pragma unroll
            for (int r2 = 0; r2 < 4; ++r2) {
                const int qi = row0 + r2;
                float val = acc[i][j][r2] * 0.125f;
                val = (key <= qi) ? val * zm : 0.f;
                Sout[((size_t)bh*S + qi)*S + key] = (bf16_t)val;
                rmax[r2] = fmaxf(rmax[r2], val);
            }
        }
        #pragma unroll
        for (int r2 = 0; r2 < 4; ++r2) {
            float rm = rmax[r2];
            rm = fmaxf(rm, __shfl_xor(rm, 1, 64));
            rm = fmaxf(rm, __shfl_xor(rm, 2, 64));
            rm = fmaxf(rm, __shfl_xor(rm, 4, 64));
            rm = fmaxf(rm, __shfl_xor(rm, 8, 64));
            if (lr == 0)
                tm[wr + i*16 + (l >> 4)*4 + r2][wc >> 6] = rm;
        }
    }
    __syncthreads();
    if (tid < 128)
        tmax[((size_t)bh*S + q0 + tid)*8 + (c0 >> 7)] =
            fmaxf(tm[tid][0], tm[tid][1]);
}

// ---------------------------------------------------------------------------
// Fused softmax+PV: per (qtile of 64, bh): single pass over 8 S-tiles,
// p = exp(s - rowmax), O += MFMA(p_bf16, Vt), divide by row sum at end.
// Includes ALL keys (masked zeros contribute exp(-m) weights * v), matching
// the reference's mask-by-zero softmax.
// ---------------------------------------------------------------------------
__global__ __launch_bounds__(256) void softmax_pv(
    const bf16_t* __restrict__ Sbuf, const bf16_t* __restrict__ Vt,
    const float* __restrict__ tmax, bf16_t* __restrict__ O, int S)
{
    __shared__ __align__(16) bf16_t Sl[64*128];
    __shared__ __align__(16) bf16_t Vl[64*128];
    __shared__ float m_lds[64];
    __shared__ float sum_lds[64];
    const int tid = threadIdx.x;
    const int q0 = blockIdx.x * 64;
    const int bh = blockIdx.y, b = bh >> 4, hh = bh & 15;
    const int l = tid & 63, w = tid >> 6;
    const int lr = l & 15, lk = (l >> 4) * 8;

    if (tid < 64) {
        const float* tp = tmax + ((size_t)bh*S + q0 + tid)*8;
        float m = tp[0];
        #pragma unroll
        for (int t = 1; t < 8; ++t) m = fmaxf(m, tp[t]);
        m_lds[tid] = m;
    }
    __syncthreads();
    const float m_i = m_lds[w*16 + lr];

    f32x4 z4 = {0.f, 0.f, 0.f, 0.f};
    f32x4 acc[4];
    #pragma unroll
    for (int j = 0; j < 4; ++j) acc[j] = z4;
    float psum = 0.f;

    for (int kt = 0; kt < 8; ++kt) {
        const int k0 = kt * 128;
        __syncthreads();
        #pragma unroll
        for (int it = 0; it < 4; ++it) {
            const int rq = w*16 + it*4 + (l >> 4);
            GLD16(Sbuf + ((size_t)bh*S + q0 + rq)*S + k0 + (l & 15)*8,
                  Sl + (w*4 + it)*512);
            GLD16(Vt + ((size_t)bh*HDIM + rq)*S + k0 + (l & 15)*8,
                  Vl + (w*4 + it)*512);
        }
        __syncthreads();
        #pragma unroll
        for (int kk = 0; kk < 4; ++kk) {
            bf16x8 sraw = *(const bf16x8*)&Sl[(w*16 + lr)*128 + kk*32 + lk];
            bf16x8 pa;
            #pragma unroll
            for (int e = 0; e < 8; ++e) {
                float p = expf((float)sraw[e] - m_i);
                psum += p;
                pa[e] = (bf16_t)p;
            }
            #pragma unroll
            for (int j = 0; j < 4; ++j) {
                bf16x8 bfr = *(const bf16x8*)&Vl[(j*16 + lr)*128 + kk*32 + lk];
                acc[j] = MFMA16(pa, bfr, acc[j]);
            }
        }
    }

    psum += __shfl_xor(psum, 16, 64);
    psum += __shfl_xor(psum, 32, 64);
    if ((l >> 4) == 0) sum_lds[w*16 + lr] = psum;
    __syncthreads();

    #pragma unroll
    for (int r2 = 0; r2 < 4; ++r2) {
        const int rloc = w*16 + (l >> 4)*4 + r2;
        const float inv = 1.0f / sum_lds[rloc];
        const size_t rowbase = (size_t)(b*S + q0 + rloc)*DD + hh*HDIM;
        #pragma unroll
        for (int j = 0; j < 4; ++j)
            O[rowbase + j*16 + lr] = (bf16_t)(acc[j][r2] * inv);
    }
}

// ---------------------------------------------------------------------------
extern "C" void kernel_launch(void* const* d_in, const int* in_sizes, int n_in,
                              void* d_out, int out_size, void* d_ws, size_t ws_size,
                              hipStream_t stream)
{
    const int S = SEQ;
    const int B = in_sizes[0] / S;     // 2
    const int M = B * S;               // 2048
    const int BH = B * HEADS;          // 32

    const int*   x       = (const int*)  d_in[0];
    const float* tok_emb = (const float*)d_in[2];
    const float* pos_emb = (const float*)d_in[3];
    const float* rif     = (const float*)d_in[4];
    const float* rbias   = (const float*)d_in[5];
    const float* brif    = (const float*)d_in[6];
    const float* bbias   = (const float*)d_in[7];
    const float* lna     = (const float*)d_in[8];
    const float* qw      = (const float*)d_in[9];
    const float* qb      = (const float*)d_in[10];
    const float* kw      = (const float*)d_in[11];
    const float* vw      = (const float*)d_in[12];
    const float* vbias   = (const float*)d_in[13];
    const float* ow      = (const float*)d_in[14];
    const float* ob      = (const float*)d_in[15];
    const float* factor  = (const float*)d_in[16];
    const float* lnc     = (const float*)d_in[17];
    const float* w1      = (const float*)d_in[18];
    const float* b1      = (const float*)d_in[19];
    const float* w2      = (const float*)d_in[20];
    const float* b2      = (const float*)d_in[21];
    const float* lnd     = (const float*)d_in[22];

    char* ob_ = (char*)d_out;
    const size_t MiB = 1024*1024;
    float*  h      = (float*)(ob_ + 0*MiB);      // 8 MiB
    float*  h2     = (float*)(ob_ + 8*MiB);      // 8 MiB
    bf16_t* qbf    = (bf16_t*)(ob_ + 16*MiB);    // 4 MiB
    bf16_t* kbf    = (bf16_t*)(ob_ + 20*MiB);    // 4 MiB
    bf16_t* vt     = (bf16_t*)(ob_ + 24*MiB);    // 4 MiB  Vt[b][h][d][S]
    bf16_t* attno  = (bf16_t*)(ob_ + 28*MiB);    // 4 MiB
    bf16_t* m1     = (bf16_t*)(ob_ + 32*MiB);    // 16 MiB
    float*  zmult  = (float*)(ob_ + 48*MiB);     // 128 KiB
    float*  tmax   = (float*)(ob_ + 49*MiB);     // 1 MiB
    float*  ctab   = (float*)(ob_ + 50*MiB);     // 128 KiB
    float*  stab   = (float*)(ob_ + 51*MiB);     // 128 KiB
    bf16_t* qw_bf  = (bf16_t*)(ob_ + 64*MiB);    // 8 MiB (4 layers)
    bf16_t* kw_bf  = (bf16_t*)(ob_ + 72*MiB);
    bf16_t* vw_bf  = (bf16_t*)(ob_ + 80*MiB);
    bf16_t* ow_bf  = (bf16_t*)(ob_ + 88*MiB);
    bf16_t* w1_bf  = (bf16_t*)(ob_ + 96*MiB);    // 32 MiB
    bf16_t* w2_bf  = (bf16_t*)(ob_ + 128*MiB);   // 32 MiB
    bf16_t* Sbuf   = (bf16_t*)(ob_ + 160*MiB);   // 64 MiB -> ends 224 < 250 MiB

    bf16_t* hn      = (bf16_t*)d_ws;             // 4 MiB
    bf16_t* temb_bf = (bf16_t*)((char*)d_ws + 4*MiB);
    const bool big_ws = ws_size >= (size_t)(70*MiB);

    const long NW_D = (long)NLAYER * DD * DD;
    const long NW_F = (long)NLAYER * FFDIM * DD;
    const long NW_E = (long)NVOCAB * DD;
    cvt_kernel<<<NW_D/2048, 256, 0, stream>>>(qw, qw_bf, NW_D);
    cvt_kernel<<<NW_D/2048, 256, 0, stream>>>(kw, kw_bf, NW_D);
    cvt_kernel<<<NW_D/2048, 256, 0, stream>>>(vw, vw_bf, NW_D);
    cvt_kernel<<<NW_D/2048, 256, 0, stream>>>(ow, ow_bf, NW_D);
    cvt_kernel<<<NW_F/2048, 256, 0, stream>>>(w1, w1_bf, NW_F);
    cvt_kernel<<<NW_F/2048, 256, 0, stream>>>(w2, w2_bf, NW_F);
    if (big_ws)
        cvt_kernel<<<(NW_E+2047)/2048, 256, 0, stream>>>(tok_emb, temb_bf, NW_E);
    ropetab_kernel<<<(S*32)/256, 256, 0, stream>>>(brif, bbias, ctab, stab);

    dim3 gD(DD/128,     M/128);
    dim3 gF(FFDIM/128,  M/128);
    dim3 gV(NVOCAB/128, M/128);
    dim3 gQKV(3*DD/128, M/128);
    dim3 gQK(S/128, S/128, BH);
    dim3 gSPV(S/64, BH);

    embed_rope_kernel<<<M, 512, 0, stream>>>(x, tok_emb, pos_emb, rif, rbias, h, S);

    for (int l = 0; l < NLAYER; ++l) {
        const size_t wo = (size_t)l * DD * DD;
        const size_t fo = (size_t)l * FFDIM * DD;
        rmsnorm_kernel<<<M, 256, 0, stream>>>(h, lna + l*DD, hn);
        qkv_gemm<<<gQKV, 256, 0, stream>>>(hn, qw_bf + wo, kw_bf + wo, vw_bf + wo,
                                           qb + l*DD, vbias + l*DD, ctab, stab,
                                           factor + l, qbf, kbf, vt, zmult, S);
        qk_kernel<<<gQK, 256, 0, stream>>>(qbf, kbf, zmult, Sbuf, tmax, S);
        softmax_pv<<<gSPV, 256, 0, stream>>>(Sbuf, vt, tmax, attno, S);
        // h2 = attno @ ow^T + ob + h
        gemm_bf<<<gD, 256, 0, stream>>>(attno, ow_bf + wo, ob + l*DD, h, nullptr,
                                        h2, nullptr, M, DD, DD, 0, 0, 0);
        rmsnorm_kernel<<<M, 256, 0, stream>>>(h2, lnc + l*DD, hn);
        gemm_bf<<<gF, 256, 0, stream>>>(hn, w1_bf + fo, b1 + l*FFDIM, nullptr, nullptr,
                                        nullptr, m1, M, FFDIM, DD, 1, 1, 0);
        // h_new = m1 @ w2^T + b2 + h2 + h   (== 2*h_old + attn + mlp)
        gemm_bf<<<gD, 256, 0, stream>>>(m1, w2_bf + fo, b2 + l*DD, h2, h,
                                        h, nullptr, M, DD, FFDIM, 0, 0, 0);
    }

    rmsnorm_kernel<<<M, 256, 0, stream>>>(h, lnd, hn);
    if (big_ws)
        gemm_bf<<<gV, 256, 0, stream>>>(hn, temb_bf, nullptr, nullptr, nullptr,
                                        (float*)d_out, nullptr, M, NVOCAB, DD, 0, 0, 1);
    else
        gemm_bfw32<<<gV, 256, 0, stream>>>(hn, tok_emb, (float*)d_out, M, NVOCAB, DD);
}

// Round 6
// 1575.175 us; speedup vs baseline: 5.1623x; 1.0683x over previous
//
#include <hip/hip_runtime.h>
#include <hip/hip_bf16.h>

#define DD 1024
#define HEADS 16
#define HDIM 64
#define NLAYER 4
#define FFDIM 4096
#define NVOCAB 32000
#define SEQ 1024

typedef __bf16 bf16_t;
typedef __bf16 bf16x8 __attribute__((ext_vector_type(8)));
typedef float f32x4 __attribute__((ext_vector_type(4)));

#define MFMA16(a, b, c) __builtin_amdgcn_mfma_f32_16x16x32_bf16((a), (b), (c), 0, 0, 0)

// async global->LDS, 16B per lane, dest = wave-uniform base + lane*16
#define GLD16(gp, lp) \
    __builtin_amdgcn_global_load_lds( \
        (const __attribute__((address_space(1))) void*)(gp), \
        (__attribute__((address_space(3))) void*)(lp), 16, 0, 0)

static __device__ __forceinline__ bf16x8 pack8(float4 u, float4 v) {
    bf16x8 r;
    r[0] = (bf16_t)u.x; r[1] = (bf16_t)u.y; r[2] = (bf16_t)u.z; r[3] = (bf16_t)u.w;
    r[4] = (bf16_t)v.x; r[5] = (bf16_t)v.y; r[6] = (bf16_t)v.z; r[7] = (bf16_t)v.w;
    return r;
}

// ---------------------------------------------------------------------------
// f32 -> bf16 bulk convert (weights, once per launch). n % 2048 == 0.
// ---------------------------------------------------------------------------
__global__ __launch_bounds__(256) void cvt_kernel(
    const float* __restrict__ src, bf16_t* __restrict__ dst, long n)
{
    long i = ((long)blockIdx.x * 256 + threadIdx.x) * 8;
    if (i < n) {
        float4 a = *(const float4*)(src + i);
        float4 b = *(const float4*)(src + i + 4);
        *(bf16x8*)(dst + i) = pack8(a, b);
    }
}

// ---------------------------------------------------------------------------
// Head-rope cos/sin tables: [S][32]
// ---------------------------------------------------------------------------
__global__ __launch_bounds__(256) void ropetab_kernel(
    const float* __restrict__ inv_freq, const float* __restrict__ rbias,
    float* __restrict__ ctab, float* __restrict__ stab)
{
    int idx = blockIdx.x * 256 + threadIdx.x;     // s*32 + i
    int s = idx >> 5, i = idx & 31;
    float fr = (float)s * inv_freq[i] + rbias[idx];
    ctab[idx] = cosf(fr);
    stab[idx] = sinf(fr);
}

// ---------------------------------------------------------------------------
// Embedding + decoder-level rotary
// ---------------------------------------------------------------------------
__global__ __launch_bounds__(512) void embed_rope_kernel(
    const int* __restrict__ x, const float* __restrict__ tok_emb,
    const float* __restrict__ pos_emb, const float* __restrict__ inv_freq,
    const float* __restrict__ rbias, float* __restrict__ h, int S)
{
    const int row = blockIdx.x;      // b*S + s
    const int s = row % S;
    const int i = threadIdx.x;       // 0..511 pair index
    const int tok = x[row];
    const float* e = tok_emb + (size_t)tok * DD;
    const float* p = pos_emb + (size_t)s * DD;
    float a = e[2*i]   + p[2*i];
    float b = e[2*i+1] + p[2*i+1];
    float fr = (float)s * inv_freq[i] + rbias[(size_t)s * (DD/2) + i];
    float c = cosf(fr), sn = sinf(fr);
    h[(size_t)row*DD + 2*i]   = a*c - b*sn;
    h[(size_t)row*DD + 2*i+1] = a*sn + b*c;
}

// ---------------------------------------------------------------------------
// RMSNorm with bf16 output
// ---------------------------------------------------------------------------
__global__ __launch_bounds__(256) void rmsnorm_kernel(
    const float* __restrict__ x, const float* __restrict__ w,
    bf16_t* __restrict__ y)
{
    const int row = blockIdx.x;
    const float* xr = x + (size_t)row * DD;
    float ss = 0.f;
    for (int j = threadIdx.x; j < DD; j += 256) { float v = xr[j]; ss += v*v; }
    for (int off = 32; off > 0; off >>= 1) ss += __shfl_down(ss, off, 64);
    __shared__ float r[4];
    if ((threadIdx.x & 63) == 0) r[threadIdx.x >> 6] = ss;
    __syncthreads();
    float tot = r[0] + r[1] + r[2] + r[3];
    float sc = rsqrtf(tot * (1.0f/(float)DD) + 1e-8f);
    for (int j = threadIdx.x; j < DD; j += 256)
        y[(size_t)row*DD + j] = (bf16_t)(xr[j] * sc * w[j]);
}

// ---------------------------------------------------------------------------
// V tile-suffix sums: vsuf[bh][t][d] = sum_{k >= 128t} Vt[bh][d][k], t=1..7
// ---------------------------------------------------------------------------
__global__ __launch_bounds__(64) void vsuf_kernel(
    const bf16_t* __restrict__ Vt, float* __restrict__ vsuf, int S)
{
    const int bh = blockIdx.x;
    const int d = threadIdx.x;
    const bf16_t* vp = Vt + ((size_t)bh*HDIM + d)*S;
    float acc = 0.f;
    for (int t = 7; t >= 1; --t) {
        #pragma unroll 8
        for (int k = t*128; k < t*128 + 128; ++k) acc += (float)vp[k];
        vsuf[((size_t)bh*8 + t)*64 + d] = acc;
    }
}

// ---------------------------------------------------------------------------
// bf16 MFMA GEMM, reg-prefetch schedule: per K-step
//   B1(sync: vmcnt drained, tile ready) -> ds_read 16 frags to regs ->
//   B2(sync: lgkm drained, LDS free) -> issue next tile's GLD16 ->
//   MFMA from regs (overlaps the in-flight loads).
// modes: 0 = f32 C; 1 = bf16 Cb. swz=1: n-major XCD-chunked block swizzle.
// ---------------------------------------------------------------------------
__global__ __launch_bounds__(256) void gemm_bf(
    const bf16_t* __restrict__ A, const bf16_t* __restrict__ W,
    const float* __restrict__ bias, const float* __restrict__ add1,
    const float* __restrict__ add2, float* __restrict__ C,
    bf16_t* __restrict__ Cb,
    int M, int N, int K, int relu, int mode, int swz)
{
    __shared__ __align__(16) bf16_t As[128*64];
    __shared__ __align__(16) bf16_t Bs[128*64];
    const int tid = threadIdx.x;
    int bx = blockIdx.x, by = blockIdx.y;
    if (swz) {
        const int nbx = gridDim.x, nby = gridDim.y;
        const int nwg = nbx * nby;             // divisible by 8
        const int lin = by * nbx + bx;
        const int wg  = (lin & 7) * (nwg >> 3) + (lin >> 3);
        bx = wg / nby;                         // n-major: same-n blocks adjacent
        by = wg % nby;
    }
    const int m0 = by * 128, n0 = bx * 128;
    const int l = tid & 63, w = tid >> 6;
    const int wr = (w >> 1) * 64, wc = (w & 1) * 64;
    const int lr = l & 15, lk = (l >> 4) * 8;

    const int srow = l >> 3, scol = (l & 7) * 8;
    const bf16_t* Ag = A + (size_t)(m0 + w*32 + srow) * K + scol;
    const bf16_t* Wg = W + (size_t)(n0 + w*32 + srow) * K + scol;

    f32x4 z4 = {0.f, 0.f, 0.f, 0.f};
    f32x4 acc[4][4];
    #pragma unroll
    for (int i = 0; i < 4; ++i)
        #pragma unroll
        for (int j = 0; j < 4; ++j) acc[i][j] = z4;

    // prologue: stage first tile
    #pragma unroll
    for (int it = 0; it < 4; ++it) {
        GLD16(Ag + (size_t)(it*8)*K, As + (w*4 + it)*512);
        GLD16(Wg + (size_t)(it*8)*K, Bs + (w*4 + it)*512);
    }

    for (int k0 = 0; k0 < K; k0 += 64) {
        __syncthreads();                       // B1: tile landed for all waves
        bf16x8 afr[8], bfr[8];
        #pragma unroll
        for (int kk = 0; kk < 2; ++kk)
            #pragma unroll
            for (int i = 0; i < 4; ++i) {
                afr[kk*4+i] = *(const bf16x8*)&As[(wr + i*16 + lr)*64 + kk*32 + lk];
                bfr[kk*4+i] = *(const bf16x8*)&Bs[(wc + i*16 + lr)*64 + kk*32 + lk];
            }
        __syncthreads();                       // B2: all reads done, LDS free
        if (k0 + 64 < K) {
            #pragma unroll
            for (int it = 0; it < 4; ++it) {
                GLD16(Ag + (size_t)(it*8)*K + k0 + 64, As + (w*4 + it)*512);
                GLD16(Wg + (size_t)(it*8)*K + k0 + 64, Bs + (w*4 + it)*512);
            }
        }
        #pragma unroll
        for (int kk = 0; kk < 2; ++kk)
            #pragma unroll
            for (int i = 0; i < 4; ++i)
                #pragma unroll
                for (int j = 0; j < 4; ++j)
                    acc[i][j] = MFMA16(afr[kk*4+i], bfr[kk*4+j], acc[i][j]);
    }

    #pragma unroll
    for (int i = 0; i < 4; ++i) {
        #pragma unroll
        for (int j = 0; j < 4; ++j) {
            const int col  = n0 + wc + j*16 + lr;
            const int row0 = m0 + wr + i*16 + (l >> 4)*4;
            const float bv = bias ? bias[col] : 0.f;
            #pragma unroll
            for (int r2 = 0; r2 < 4; ++r2) {
                const int row = row0 + r2;
                float val = acc[i][j][r2] + bv;
                if (add1) val += add1[(size_t)row*N + col];
                if (add2) val += add2[(size_t)row*N + col];
                if (relu) val = fmaxf(val, 0.f);
                if (mode == 0) C[(size_t)row*N + col] = val;
                else           Cb[(size_t)row*N + col] = (bf16_t)val;
            }
        }
    }
}

// ---------------------------------------------------------------------------
// Fallback logits GEMM (A bf16 via gload_lds, W f32 reg-staged). Unchanged.
// ---------------------------------------------------------------------------
__global__ __launch_bounds__(256) void gemm_bfw32(
    const bf16_t* __restrict__ A, const float* __restrict__ W,
    float* __restrict__ C, int M, int N, int K)
{
    __shared__ __align__(16) bf16_t As[128*64];
    __shared__ __align__(16) bf16_t Bs[128*64];
    const int tid = threadIdx.x;
    const int m0 = blockIdx.y * 128, n0 = blockIdx.x * 128;
    const int l = tid & 63, w = tid >> 6;
    const int wr = (w >> 1) * 64, wc = (w & 1) * 64;
    const int lr = l & 15, lk = (l >> 4) * 8;
    const int srow = l >> 3, scol = (l & 7) * 8;
    const bf16_t* Ag = A + (size_t)(m0 + w*32 + srow) * K + scol;
    const int r = tid >> 1, half = (tid & 1) * 32;
    const float* Wp = W + (size_t)(n0 + r) * K + half;

    f32x4 z4 = {0.f, 0.f, 0.f, 0.f};
    f32x4 acc[4][4];
    #pragma unroll
    for (int i = 0; i < 4; ++i)
        #pragma unroll
        for (int j = 0; j < 4; ++j) acc[i][j] = z4;

    for (int k0 = 0; k0 < K; k0 += 64) {
        float4 wv[8];
        #pragma unroll
        for (int j = 0; j < 8; ++j) wv[j] = *(const float4*)(Wp + k0 + 4*j);
        __syncthreads();
        #pragma unroll
        for (int it = 0; it < 4; ++it)
            GLD16(Ag + (size_t)(it*8)*K + k0, As + (w*4 + it)*512);
        #pragma unroll
        for (int j = 0; j < 4; ++j)
            *(bf16x8*)&Bs[r*64 + half + 8*j] = pack8(wv[2*j], wv[2*j+1]);
        __syncthreads();
        #pragma unroll
        for (int kk = 0; kk < 2; ++kk) {
            bf16x8 afr[4], bfr[4];
            #pragma unroll
            for (int i = 0; i < 4; ++i)
                afr[i] = *(const bf16x8*)&As[(wr + i*16 + lr)*64 + kk*32 + lk];
            #pragma unroll
            for (int j = 0; j < 4; ++j)
                bfr[j] = *(const bf16x8*)&Bs[(wc + j*16 + lr)*64 + kk*32 + lk];
            #pragma unroll
            for (int i = 0; i < 4; ++i)
                #pragma unroll
                for (int j = 0; j < 4; ++j)
                    acc[i][j] = MFMA16(afr[i], bfr[j], acc[i][j]);
        }
    }
    #pragma unroll
    for (int i = 0; i < 4; ++i)
        #pragma unroll
        for (int j = 0; j < 4; ++j) {
            const int col  = n0 + wc + j*16 + lr;
            const int row0 = m0 + wr + i*16 + (l >> 4)*4;
            #pragma unroll
            for (int r2 = 0; r2 < 4; ++r2)
                C[(size_t)(row0 + r2)*N + col] = acc[i][j][r2];
        }
}

// ---------------------------------------------------------------------------
// Fused QKV GEMM (M x 3072): seg 0=q (rope, ->qbf), 1=k (rope, ->kbf, zmult),
// 2=v (->Vt[b][h][d][S]). Rope pairs = adjacent cols = shfl_xor(val,1).
// Same reg-prefetch schedule as gemm_bf.
// ---------------------------------------------------------------------------
__global__ __launch_bounds__(256) void qkv_gemm(
    const bf16_t* __restrict__ A, const bf16_t* __restrict__ Wq,
    const bf16_t* __restrict__ Wk, const bf16_t* __restrict__ Wv,
    const float* __restrict__ qb, const float* __restrict__ vbias,
    const float* __restrict__ ctab, const float* __restrict__ stab,
    const float* __restrict__ fptr,
    bf16_t* __restrict__ qbf, bf16_t* __restrict__ kbf,
    bf16_t* __restrict__ vt, float* __restrict__ zmult, int S)
{
    __shared__ __align__(16) bf16_t As[128*64];
    __shared__ __align__(16) bf16_t Bs[128*64];
    const int tid = threadIdx.x;
    const int seg = blockIdx.x >> 3;              // 0=q 1=k 2=v
    const int n0  = (blockIdx.x & 7) * 128;       // col within segment
    const int m0  = blockIdx.y * 128;
    const bf16_t* W = (seg == 0) ? Wq : (seg == 1) ? Wk : Wv;
    const int K = DD;
    const int l = tid & 63, w = tid >> 6;
    const int wr = (w >> 1) * 64, wc = (w & 1) * 64;
    const int lr = l & 15, lk = (l >> 4) * 8;

    const int srow = l >> 3, scol = (l & 7) * 8;
    const bf16_t* Ag = A + (size_t)(m0 + w*32 + srow) * K + scol;
    const bf16_t* Wg = W + (size_t)(n0 + w*32 + srow) * K + scol;

    f32x4 z4 = {0.f, 0.f, 0.f, 0.f};
    f32x4 acc[4][4];
    #pragma unroll
    for (int i = 0; i < 4; ++i)
        #pragma unroll
        for (int j = 0; j < 4; ++j) acc[i][j] = z4;

    #pragma unroll
    for (int it = 0; it < 4; ++it) {
        GLD16(Ag + (size_t)(it*8)*K, As + (w*4 + it)*512);
        GLD16(Wg + (size_t)(it*8)*K, Bs + (w*4 + it)*512);
    }

    for (int k0 = 0; k0 < K; k0 += 64) {
        __syncthreads();
        bf16x8 afr[8], bfr[8];
        #pragma unroll
        for (int kk = 0; kk < 2; ++kk)
            #pragma unroll
            for (int i = 0; i < 4; ++i) {
                afr[kk*4+i] = *(const bf16x8*)&As[(wr + i*16 + lr)*64 + kk*32 + lk];
                bfr[kk*4+i] = *(const bf16x8*)&Bs[(wc + i*16 + lr)*64 + kk*32 + lk];
            }
        __syncthreads();
        if (k0 + 64 < K) {
            #pragma unroll
            for (int it = 0; it < 4; ++it) {
                GLD16(Ag + (size_t)(it*8)*K + k0 + 64, As + (w*4 + it)*512);
                GLD16(Wg + (size_t)(it*8)*K + k0 + 64, Bs + (w*4 + it)*512);
            }
        }
        #pragma unroll
        for (int kk = 0; kk < 2; ++kk)
            #pragma unroll
            for (int i = 0; i < 4; ++i)
                #pragma unroll
                for (int j = 0; j < 4; ++j)
                    acc[i][j] = MFMA16(afr[kk*4+i], bfr[kk*4+j], acc[i][j]);
    }

    float zf = 0.f;
    if (seg == 1) {
        float f = fptr[0];
        float sp = (f > 20.f) ? f : log1pf(expf(f));
        zf = fminf(fmaxf(sp, 1e-5f), 0.1f);
    }

    #pragma unroll
    for (int i = 0; i < 4; ++i) {
        #pragma unroll
        for (int j = 0; j < 4; ++j) {
            const int col = n0 + wc + j*16 + lr;          // 0..1023 within seg
            const float bv = (seg == 0) ? qb[col] : (seg == 2) ? vbias[col] : 0.f;
            const int d  = col & 63;
            const int hh = col >> 6;
            const int pi = d >> 1;
            #pragma unroll
            for (int r2 = 0; r2 < 4; ++r2) {
                const int row = m0 + wr + i*16 + (l >> 4)*4 + r2;
                const int s  = row & (SEQ - 1);
                const int bb = row >> 10;
                float val = acc[i][j][r2] + bv;
                if (seg < 2) {
                    // rope pair (even,odd) lives in lanes lr, lr^1
                    float partner = __shfl_xor(val, 1, 64);
                    float c  = ctab[s*32 + pi];
                    float sn = stab[s*32 + pi];
                    float out = ((d & 1) == 0) ? (val*c - partner*sn)
                                               : (partner*sn + val*c);
                    if (seg == 0) {
                        qbf[(size_t)row*DD + col] = (bf16_t)out;
                    } else {
                        kbf[(size_t)row*DD + col] = (bf16_t)out;
                        if (d == 0)
                            zmult[(size_t)(bb*HEADS + hh)*S + s] =
                                (out == 0.0f) ? zf : 1.0f;
                    }
                } else {
                    vt[((size_t)(bb*HEADS + hh)*HDIM + d)*SEQ + s] = (bf16_t)val;
                }
            }
        }
    }
}

// ---------------------------------------------------------------------------
// QK^T, causal tiles only. grid (36 tri-pairs, 1, BH). Writes bf16 scores
// (masked-in-tile entries exact 0) + per-tile row maxes.
// ---------------------------------------------------------------------------
__global__ __launch_bounds__(256) void qk_kernel(
    const bf16_t* __restrict__ qbf, const bf16_t* __restrict__ kbf,
    const float* __restrict__ zmult, bf16_t* __restrict__ Sout,
    float* __restrict__ tmax, int S)
{
    __shared__ __align__(16) bf16_t As[128*64];
    __shared__ __align__(16) bf16_t Bs[128*64];
    __shared__ float tm[128][2];
    const int tid = threadIdx.x;
    const int bh = blockIdx.z;
    const int b = bh >> 4, hh = bh & 15;
    // triangular index -> (qt, kt), kt <= qt
    int xindex = blockIdx.x, qt = 0, kt = 0;
    #pragma unroll
    for (int qq = 0; qq < 8; ++qq) {
        int base = qq*(qq+1)/2;
        if (xindex >= base && xindex < base + qq + 1) { qt = qq; kt = xindex - base; }
    }
    const int q0 = qt * 128, c0 = kt * 128;
    const int l = tid & 63, w = tid >> 6;
    const int wr = (w >> 1) * 64, wc = (w & 1) * 64;
    const int lr = l & 15, lk = (l >> 4) * 8;

    const int srow = l >> 3, scol = (l & 7) * 8;
    {
        const bf16_t* Ag = qbf + (size_t)(b*S + q0 + w*32 + srow)*DD + hh*HDIM + scol;
        const bf16_t* Bg = kbf + (size_t)(b*S + c0 + w*32 + srow)*DD + hh*HDIM + scol;
        #pragma unroll
        for (int it = 0; it < 4; ++it) {
            GLD16(Ag + (size_t)(it*8)*DD, As + (w*4 + it)*512);
            GLD16(Bg + (size_t)(it*8)*DD, Bs + (w*4 + it)*512);
        }
        __syncthreads();
    }

    f32x4 z4 = {0.f, 0.f, 0.f, 0.f};
    f32x4 acc[4][4];
    #pragma unroll
    for (int i = 0; i < 4; ++i)
        #pragma unroll
        for (int j = 0; j < 4; ++j) acc[i][j] = z4;

    #pragma unroll
    for (int kk = 0; kk < 2; ++kk) {
        bf16x8 afr[4], bfr[4];
        #pragma unroll
        for (int i = 0; i < 4; ++i)
            afr[i] = *(const bf16x8*)&As[(wr + i*16 + lr)*64 + kk*32 + lk];
        #pragma unroll
        for (int j = 0; j < 4; ++j)
            bfr[j] = *(const bf16x8*)&Bs[(wc + j*16 + lr)*64 + kk*32 + lk];
        #pragma unroll
        for (int i = 0; i < 4; ++i)
            #pragma unroll
            for (int j = 0; j < 4; ++j)
                acc[i][j] = MFMA16(afr[i], bfr[j], acc[i][j]);
    }

    #pragma unroll
    for (int i = 0; i < 4; ++i) {
        float rmax[4] = {-3.0e38f, -3.0e38f, -3.0e38f, -3.0e38f};
        #pragma unroll
        for (int j = 0; j < 4; ++j) {
            const int key = c0 + wc + j*16 + lr;
            const float zm = zmult[(size_t)bh*S + key];
            const int row0 = q0 + wr + i*16 + (l >> 4)*4;
            #pragma unroll
            for (int r2 = 0; r2 < 4; ++r2) {
                const int qi = row0 + r2;
                float val = acc[i][j][r2] * 0.125f;
                val = (key <= qi) ? val * zm : 0.f;
                Sout[((size_t)bh*S + qi)*S + key] = (bf16_t)val;
                rmax[r2] = fmaxf(rmax[r2], val);
            }
        }
        #pragma unroll
        for (int r2 = 0; r2 < 4; ++r2) {
            float rm = rmax[r2];
            rm = fmaxf(rm, __shfl_xor(rm, 1, 64));
            rm = fmaxf(rm, __shfl_xor(rm, 2, 64));
            rm = fmaxf(rm, __shfl_xor(rm, 4, 64));
            rm = fmaxf(rm, __shfl_xor(rm, 8, 64));
            if (lr == 0)
                tm[wr + i*16 + (l >> 4)*4 + r2][wc >> 6] = rm;
        }
    }
    __syncthreads();
    if (tid < 128)
        tmax[((size_t)bh*S + q0 + tid)*8 + kt] =
            fmaxf(tm[tid][0], tm[tid][1]);
}

// ---------------------------------------------------------------------------
// Fused softmax+PV, causal: per (64-row qtile, bh), process key tiles
// 0..ktm (ktm = q0>>7); the fully-masked tail (cnt keys) is added
// analytically: psum += cnt*exp(-m); acc += exp(-m)*Vsuf[ktm+1].
// Matches the reference's mask-by-zero softmax exactly.
// ---------------------------------------------------------------------------
__global__ __launch_bounds__(256) void softmax_pv(
    const bf16_t* __restrict__ Sbuf, const bf16_t* __restrict__ Vt,
    const float* __restrict__ tmax, const float* __restrict__ vsuf,
    bf16_t* __restrict__ O, int S)
{
    __shared__ __align__(16) bf16_t Sl[64*128];
    __shared__ __align__(16) bf16_t Vl[64*128];
    __shared__ float m_lds[64];
    __shared__ float sum_lds[64];
    const int tid = threadIdx.x;
    const int q0 = blockIdx.x * 64;
    const int bh = blockIdx.y, b = bh >> 4, hh = bh & 15;
    const int l = tid & 63, w = tid >> 6;
    const int lr = l & 15, lk = (l >> 4) * 8;
    const int ktm = q0 >> 7;                 // last causal 128-key tile
    const int cnt = S - 128*(ktm + 1);       // fully-masked tail key count

    if (tid < 64) {
        const float* tp = tmax + ((size_t)bh*S + q0 + tid)*8;
        float m = (cnt > 0) ? 0.f : -3.0e38f;   // masked zeros participate
        for (int t = 0; t <= ktm; ++t) m = fmaxf(m, tp[t]);
        m_lds[tid] = m;
    }
    __syncthreads();
    const float m_i = m_lds[w*16 + lr];

    f32x4 z4 = {0.f, 0.f, 0.f, 0.f};
    f32x4 acc[4];
    #pragma unroll
    for (int j = 0; j < 4; ++j) acc[j] = z4;
    float psum = 0.f;

    for (int kkt = 0; kkt <= ktm; ++kkt) {
        const int k0 = kkt * 128;
        __syncthreads();
        #pragma unroll
        for (int it = 0; it < 4; ++it) {
            const int rq = w*16 + it*4 + (l >> 4);
            GLD16(Sbuf + ((size_t)bh*S + q0 + rq)*S + k0 + (l & 15)*8,
                  Sl + (w*4 + it)*512);
            GLD16(Vt + ((size_t)bh*HDIM + rq)*S + k0 + (l & 15)*8,
                  Vl + (w*4 + it)*512);
        }
        __syncthreads();
        #pragma unroll
        for (int kk = 0; kk < 4; ++kk) {
            bf16x8 sraw = *(const bf16x8*)&Sl[(w*16 + lr)*128 + kk*32 + lk];
            bf16x8 pa;
            #pragma unroll
            for (int e = 0; e < 8; ++e) {
                float p = expf((float)sraw[e] - m_i);
                psum += p;
                pa[e] = (bf16_t)p;
            }
            #pragma unroll
            for (int j = 0; j < 4; ++j) {
                bf16x8 bfr = *(const bf16x8*)&Vl[(j*16 + lr)*128 + kk*32 + lk];
                acc[j] = MFMA16(pa, bfr, acc[j]);
            }
        }
    }

    psum += __shfl_xor(psum, 16, 64);
    psum += __shfl_xor(psum, 32, 64);
    if ((l >> 4) == 0)
        sum_lds[w*16 + lr] = psum + (float)cnt * expf(0.f - m_i);
    __syncthreads();

    #pragma unroll
    for (int r2 = 0; r2 < 4; ++r2) {
        const int rloc = w*16 + (l >> 4)*4 + r2;
        const float minv = m_lds[rloc];
        const float inv = 1.0f / sum_lds[rloc];
        const size_t rowbase = (size_t)(b*S + q0 + rloc)*DD + hh*HDIM;
        #pragma unroll
        for (int j = 0; j < 4; ++j) {
            float val = acc[j][r2];
            if (cnt > 0)
                val += expf(-minv) * vsuf[((size_t)bh*8 + ktm + 1)*64 + j*16 + lr];
            O[rowbase + j*16 + lr] = (bf16_t)(val * inv);
        }
    }
}

// ---------------------------------------------------------------------------
extern "C" void kernel_launch(void* const* d_in, const int* in_sizes, int n_in,
                              void* d_out, int out_size, void* d_ws, size_t ws_size,
                              hipStream_t stream)
{
    const int S = SEQ;
    const int B = in_sizes[0] / S;     // 2
    const int M = B * S;               // 2048
    const int BH = B * HEADS;          // 32

    const int*   x       = (const int*)  d_in[0];
    const float* tok_emb = (const float*)d_in[2];
    const float* pos_emb = (const float*)d_in[3];
    const float* rif     = (const float*)d_in[4];
    const float* rbias   = (const float*)d_in[5];
    const float* brif    = (const float*)d_in[6];
    const float* bbias   = (const float*)d_in[7];
    const float* lna     = (const float*)d_in[8];
    const float* qw      = (const float*)d_in[9];
    const float* qb      = (const float*)d_in[10];
    const float* kw      = (const float*)d_in[11];
    const float* vw      = (const float*)d_in[12];
    const float* vbias   = (const float*)d_in[13];
    const float* ow      = (const float*)d_in[14];
    const float* ob      = (const float*)d_in[15];
    const float* factor  = (const float*)d_in[16];
    const float* lnc     = (const float*)d_in[17];
    const float* w1      = (const float*)d_in[18];
    const float* b1      = (const float*)d_in[19];
    const float* w2      = (const float*)d_in[20];
    const float* b2      = (const float*)d_in[21];
    const float* lnd     = (const float*)d_in[22];

    char* ob_ = (char*)d_out;
    const size_t MiB = 1024*1024;
    float*  h      = (float*)(ob_ + 0*MiB);      // 8 MiB
    float*  h2     = (float*)(ob_ + 8*MiB);      // 8 MiB
    bf16_t* qbf    = (bf16_t*)(ob_ + 16*MiB);    // 4 MiB
    bf16_t* kbf    = (bf16_t*)(ob_ + 20*MiB);    // 4 MiB
    bf16_t* vt     = (bf16_t*)(ob_ + 24*MiB);    // 4 MiB  Vt[b][h][d][S]
    bf16_t* attno  = (bf16_t*)(ob_ + 28*MiB);    // 4 MiB
    bf16_t* m1     = (bf16_t*)(ob_ + 32*MiB);    // 16 MiB
    float*  zmult  = (float*)(ob_ + 48*MiB);     // 128 KiB
    float*  tmax   = (float*)(ob_ + 49*MiB);     // 1 MiB
    float*  ctab   = (float*)(ob_ + 50*MiB);     // 128 KiB
    float*  stab   = (float*)(ob_ + 51*MiB);     // 128 KiB
    float*  vsuf   = (float*)(ob_ + 52*MiB);     // 64 KiB
    bf16_t* qw_bf  = (bf16_t*)(ob_ + 64*MiB);    // 8 MiB (4 layers)
    bf16_t* kw_bf  = (bf16_t*)(ob_ + 72*MiB);
    bf16_t* vw_bf  = (bf16_t*)(ob_ + 80*MiB);
    bf16_t* ow_bf  = (bf16_t*)(ob_ + 88*MiB);
    bf16_t* w1_bf  = (bf16_t*)(ob_ + 96*MiB);    // 32 MiB
    bf16_t* w2_bf  = (bf16_t*)(ob_ + 128*MiB);   // 32 MiB
    bf16_t* Sbuf   = (bf16_t*)(ob_ + 160*MiB);   // 64 MiB -> ends 224 < 250 MiB

    bf16_t* hn      = (bf16_t*)d_ws;             // 4 MiB
    bf16_t* temb_bf = (bf16_t*)((char*)d_ws + 4*MiB);
    const bool big_ws = ws_size >= (size_t)(70*MiB);

    const long NW_D = (long)NLAYER * DD * DD;
    const long NW_F = (long)NLAYER * FFDIM * DD;
    const long NW_E = (long)NVOCAB * DD;
    cvt_kernel<<<NW_D/2048, 256, 0, stream>>>(qw, qw_bf, NW_D);
    cvt_kernel<<<NW_D/2048, 256, 0, stream>>>(kw, kw_bf, NW_D);
    cvt_kernel<<<NW_D/2048, 256, 0, stream>>>(vw, vw_bf, NW_D);
    cvt_kernel<<<NW_D/2048, 256, 0, stream>>>(ow, ow_bf, NW_D);
    cvt_kernel<<<NW_F/2048, 256, 0, stream>>>(w1, w1_bf, NW_F);
    cvt_kernel<<<NW_F/2048, 256, 0, stream>>>(w2, w2_bf, NW_F);
    if (big_ws)
        cvt_kernel<<<(NW_E+2047)/2048, 256, 0, stream>>>(tok_emb, temb_bf, NW_E);
    ropetab_kernel<<<(S*32)/256, 256, 0, stream>>>(brif, bbias, ctab, stab);

    dim3 gD(DD/128,     M/128);
    dim3 gF(FFDIM/128,  M/128);
    dim3 gV(NVOCAB/128, M/128);
    dim3 gQKV(3*DD/128, M/128);
    dim3 gQK(36, 1, BH);
    dim3 gSPV(S/64, BH);

    embed_rope_kernel<<<M, 512, 0, stream>>>(x, tok_emb, pos_emb, rif, rbias, h, S);

    for (int l = 0; l < NLAYER; ++l) {
        const size_t wo = (size_t)l * DD * DD;
        const size_t fo = (size_t)l * FFDIM * DD;
        rmsnorm_kernel<<<M, 256, 0, stream>>>(h, lna + l*DD, hn);
        qkv_gemm<<<gQKV, 256, 0, stream>>>(hn, qw_bf + wo, kw_bf + wo, vw_bf + wo,
                                           qb + l*DD, vbias + l*DD, ctab, stab,
                                           factor + l, qbf, kbf, vt, zmult, S);
        vsuf_kernel<<<BH, 64, 0, stream>>>(vt, vsuf, S);
        qk_kernel<<<gQK, 256, 0, stream>>>(qbf, kbf, zmult, Sbuf, tmax, S);
        softmax_pv<<<gSPV, 256, 0, stream>>>(Sbuf, vt, tmax, vsuf, attno, S);
        // h2 = attno @ ow^T + ob + h
        gemm_bf<<<gD, 256, 0, stream>>>(attno, ow_bf + wo, ob + l*DD, h, nullptr,
                                        h2, nullptr, M, DD, DD, 0, 0, 0);
        rmsnorm_kernel<<<M, 256, 0, stream>>>(h2, lnc + l*DD, hn);
        gemm_bf<<<gF, 256, 0, stream>>>(hn, w1_bf + fo, b1 + l*FFDIM, nullptr, nullptr,
                                        nullptr, m1, M, FFDIM, DD, 1, 1, 0);
        // h_new = m1 @ w2^T + b2 + h2 + h   (== 2*h_old + attn + mlp)
        gemm_bf<<<gD, 256, 0, stream>>>(m1, w2_bf + fo, b2 + l*DD, h2, h,
                                        h, nullptr, M, DD, FFDIM, 0, 0, 0);
    }

    rmsnorm_kernel<<<M, 256, 0, stream>>>(h, lnd, hn);
    if (big_ws)
        gemm_bf<<<gV, 256, 0, stream>>>(hn, temb_bf, nullptr, nullptr, nullptr,
                                        (float*)d_out, nullptr, M, NVOCAB, DD, 0, 0, 1);
    else
        gemm_bfw32<<<gV, 256, 0, stream>>>(hn, tok_emb, (float*)d_out, M, NVOCAB, DD);
}